// Round 1
// baseline (237.608 us; speedup 1.0000x reference)
//
#include <hip/hip_runtime.h>
#include <hip/hip_bf16.h>

typedef __hip_bfloat16 bh;
typedef __attribute__((ext_vector_type(8))) __bf16 bf16x8;
typedef __attribute__((ext_vector_type(4))) float f32x4;
typedef __attribute__((ext_vector_type(4))) int i32x4;
typedef __attribute__((ext_vector_type(4))) short s16x4;

#define NB 2
#define NL 4096
#define NC 512
#define NH 8
#define NDH 64
#define NM (NB * NL)          // 8192
#define LOG2E 1.4426950408889634f
#define KVBLK 8192            // elems per (bh,kt): 8KB K frags + 8KB V frags

static __device__ __forceinline__ f32x4 mfma_bf16(bf16x8 a, bf16x8 b, f32x4 c) {
    return __builtin_amdgcn_mfma_f32_16x16x32_bf16(a, b, c, 0, 0, 0);
}
static __device__ __forceinline__ f32x4 mfma16(s16x4 a, s16x4 b, f32x4 c) {
    return __builtin_amdgcn_mfma_f32_16x16x16bf16_1k(a, b, c, 0, 0, 0);
}

static __device__ __forceinline__ void st_bf4(bh* dst, float a, float b, float c, float d) {
    bh tmp[4] = {__float2bfloat16(a), __float2bfloat16(b),
                 __float2bfloat16(c), __float2bfloat16(d)};
    *(s16x4*)dst = *(const s16x4*)tmp;
}
static __device__ __forceinline__ s16x4 pk_bf4(float a, float b, float c, float d) {
    bh tmp[4] = {__float2bfloat16(a), __float2bfloat16(b),
                 __float2bfloat16(c), __float2bfloat16(d)};
    return *(const s16x4*)tmp;
}

static __device__ __forceinline__ void gload16(const bh* g, bh* l) {
    __builtin_amdgcn_global_load_lds(
        (const __attribute__((address_space(1))) void*)g,
        (__attribute__((address_space(3))) void*)l,
        16, 0, 0);
}

// ---------------------------------------------------------------------------
// Kernel 0: combined prep (unchanged).
//  z<8: x fp32 -> xf bf16 A-frag blocks (coalesced, LDS-transposed).
//  z==8: W pack (Wq,Wk,Wv,Wo fp32 -> Wf B-frag blocks).
// ---------------------------------------------------------------------------
__global__ __launch_bounds__(256, 2)
void prep(const float* __restrict__ x,
          const float* __restrict__ Wq, const float* __restrict__ Wk,
          const float* __restrict__ Wv, const float* __restrict__ Wo,
          bh* __restrict__ xf, bh* __restrict__ Wf)
{
    const int t = threadIdx.x;
    const int wave = t >> 6, lane = t & 63;
    const int quad = lane >> 4, c16 = lane & 15;

    if (blockIdx.z < 8) {
        __shared__ __align__(16) bh T[64][72];
        const int m64 = blockIdx.x, k64 = blockIdx.z;
        #pragma unroll
        for (int rep = 0; rep < 4; rep++) {
            int li = t + rep * 256;
            int r = li >> 4, c4 = (li & 15) * 4;
            float4 f = *(const float4*)&x[(size_t)(m64 * 64 + r) * 512 + k64 * 64 + c4];
            st_bf4(&T[r][c4], f.x, f.y, f.z, f.w);
        }
        __syncthreads();
        #pragma unroll
        for (int kcl = 0; kcl < 2; kcl++) {
            i32x4 v = *(const i32x4*)&T[wave * 16 + c16][kcl * 32 + quad * 8];
            size_t addr = ((size_t)(m64 * 4 + wave) * 16 + (k64 * 2 + kcl)) * 512 + lane * 8;
            *(i32x4*)&xf[addr] = v;
        }
    } else {
        if (blockIdx.x >= 64) return;
        int task = blockIdx.x * 4 + wave;
        int z = task >> 6, nt = (task >> 3) & 7, k0i = task & 7;
        const float* W = (z == 0) ? Wq : (z == 1) ? Wk : (z == 2) ? Wv : Wo;
        bh* dst = Wf + (((size_t)z * 8 + nt) * 8 + k0i) * 4096;
        #pragma unroll
        for (int kc = 0; kc < 2; kc++)
            #pragma unroll
            for (int fn = 0; fn < 4; fn++) {
                bh tmp[8];
                #pragma unroll
                for (int j = 0; j < 8; j++)
                    tmp[j] = __float2bfloat16(
                        W[(size_t)(k0i * 64 + kc * 32 + quad * 8 + j) * 512
                          + nt * 64 + fn * 16 + c16]);
                *(i32x4*)&dst[(kc * 4 + fn) * 512 + lane * 8] = *(const i32x4*)tmp;
            }
    }
}

// ---------------------------------------------------------------------------
// Kernel 1: fused QKV projection (unchanged).
// ---------------------------------------------------------------------------
__global__ __launch_bounds__(256, 2)
void qkv_gemm(const bh* __restrict__ xf, const bh* __restrict__ Wf,
              bh* __restrict__ Qb, bh* __restrict__ KVf)
{
    __shared__ __align__(16) bh smem[2][20480];  // per buf: Xl 8192 + Wl 12288 (80 KB)

    const int t = threadIdx.x;
    const int wave = t >> 6, lane = t & 63;
    const int quad = lane >> 4, c16 = lane & 15;
    const int m0 = blockIdx.x * 128;
    const int nt = blockIdx.y;
    const int m16b = m0 >> 4;

    f32x4 acc[3][2][4];
    for (int z = 0; z < 3; z++)
        for (int a = 0; a < 2; a++)
            for (int b = 0; b < 4; b++)
                for (int u = 0; u < 4; u++) acc[z][a][b][u] = 0.0f;

    auto stage = [&](int k0i, int buf) {
        bh* Xl = &smem[buf][0];
        bh* Wl = &smem[buf][8192];
        #pragma unroll
        for (int r = 0; r < 4; r++) {
            int f = wave * 4 + r;             // m16l*2 + kcl
            const bh* src = xf + ((size_t)(m16b + (f >> 1)) * 16 + k0i * 2 + (f & 1)) * 512
                          + lane * 8;
            gload16(src, &Xl[f * 512 + lane * 8]);
        }
        #pragma unroll
        for (int z = 0; z < 3; z++) {
            const bh* wz = Wf + (((size_t)z * 8 + nt) * 8 + k0i) * 4096;
            #pragma unroll
            for (int r = 0; r < 2; r++) {
                int off = (wave * 2 + r) * 512 + lane * 8;
                gload16(wz + off, &Wl[z * 4096 + off]);
            }
        }
    };

    stage(0, 0);
    for (int k0i = 0; k0i < 8; k0i++) {
        const int buf = k0i & 1;
        __syncthreads();                      // loads for k0i landed; buf^1 free
        if (k0i < 7) stage(k0i + 1, buf ^ 1);
        const bh* Xl = &smem[buf][0];
        const bh* Wl = &smem[buf][8192];
        #pragma unroll
        for (int kc = 0; kc < 2; kc++) {
            bf16x8 af0 = *(const bf16x8*)&Xl[((wave * 2 + 0) * 2 + kc) * 512 + lane * 8];
            bf16x8 af1 = *(const bf16x8*)&Xl[((wave * 2 + 1) * 2 + kc) * 512 + lane * 8];
            #pragma unroll
            for (int z = 0; z < 3; z++)
                #pragma unroll
                for (int fn = 0; fn < 4; fn++) {
                    bf16x8 bf = *(const bf16x8*)&Wl[z * 4096 + (kc * 4 + fn) * 512 + lane * 8];
                    acc[z][0][fn] = mfma_bf16(af0, bf, acc[z][0][fn]);
                    acc[z][1][fn] = mfma_bf16(af1, bf, acc[z][1][fn]);
                }
        }
        __syncthreads();
    }

    const int h = nt;
    const int b = m0 >> 12;
    const int l0 = m0 & 4095;
    const int bh_i = b * NH + h;
    const int kt0 = l0 >> 6;

    // ---- Phase Q: LDS transpose, coalesced 16B/lane stores to row-major Qb.
    {
        bh* Tq = &smem[0][0];
        #pragma unroll
        for (int fm = 0; fm < 2; fm++)
            #pragma unroll
            for (int i = 0; i < 4; i++) {
                int ll = wave * 32 + fm * 16 + quad * 4 + i;
                #pragma unroll
                for (int fn = 0; fn < 4; fn++)
                    Tq[ll * 68 + fn * 16 + c16] =
                        __float2bfloat16(acc[0][fm][fn][i] * 0.125f);
            }
        __syncthreads();
        int l = t >> 1, half = t & 1;
        bh* dst = Qb + ((size_t)bh_i * NL + l0 + l) * NDH + half * 32;
        const bh* src = &Tq[l * 68 + half * 32];
        #pragma unroll
        for (int r = 0; r < 4; r++)
            *(i32x4*)(dst + r * 8) = *(const i32x4*)(src + r * 8);
        __syncthreads();
    }

    // ---- Phase K: LDS scatter into KVf frag image (xLOG2E), coalesced copy-out.
    {
        bh* Tk = &smem[0][0];
        #pragma unroll
        for (int fm = 0; fm < 2; fm++)
            #pragma unroll
            for (int i = 0; i < 4; i++) {
                int ll = wave * 32 + fm * 16 + quad * 4 + i;
                int ktl = ll >> 6, l64 = ll & 63;
                int fk = l64 >> 4, c16t = l64 & 15;
                #pragma unroll
                for (int fn = 0; fn < 4; fn++) {
                    int d = fn * 16 + c16;
                    int kc = d >> 5, qt = (d >> 3) & 3, j = d & 7;
                    Tk[ktl * 4096 + (fk * 2 + kc) * 512 + (qt * 16 + c16t) * 8 + j] =
                        __float2bfloat16(acc[1][fm][fn][i] * LOG2E);
                }
            }
        __syncthreads();
        int idx = t * 32;
        int ktl = idx >> 12, wi = idx & 4095;
        bh* dst = KVf + (size_t)(bh_i * 64 + kt0 + ktl) * KVBLK + wi;
        #pragma unroll
        for (int r = 0; r < 4; r++)
            *(i32x4*)(dst + r * 8) = *(const i32x4*)&Tk[idx + r * 8];
    }

    // ---- V: contiguous b64 frag stores (unchanged).
    #pragma unroll
    for (int fm = 0; fm < 2; fm++) {
        int fkv = (wave * 2 + fm) & 3;
        int ktv = kt0 + (wave >> 1);
        #pragma unroll
        for (int fn = 0; fn < 4; fn++) {
            size_t addr = (size_t)(bh_i * 64 + ktv) * KVBLK + 4096
                        + (size_t)(fn * 4 + fkv) * 256 + (quad * 16 + c16) * 4;
            st_bf4(&KVf[addr], acc[2][fm][fn][0], acc[2][fm][fn][1],
                               acc[2][fm][fn][2], acc[2][fm][fn][3]);
        }
    }
}

// ---------------------------------------------------------------------------
// Kernel 2: flash attention — split-K, P-in-register PV.
// v5 (this round): T15 deferred-PV pipeline.  In iteration i:
//   QK^T(i) [MFMA]  interleaved with  PV(i-1) [MFMA, independent regs]
//   and exp/pack(i) [VALU] — independent streams keep both pipes busy
//   within a wave instead of phase-locking at the per-iter barrier.
//  - K double-buffered, prefetch distance 1 (as before).
//  - V double-buffered with one-iter LAG: stageV(i) issued in body(i),
//    consumed by PV in body(i+1) -> buffer (i-1)&1 is never overwritten
//    while PV reads it.  LDS stays 64 KB -> occupancy unchanged.
//  - P fragments ping-pong between named reg sets pfA/pfB (no runtime idx).
//  - s_setprio(1) around the compute region (T5).
// ---------------------------------------------------------------------------
__global__ __launch_bounds__(512, 4)
void flash_attn(const bh* __restrict__ Qb, const bh* __restrict__ KVf,
                bh* __restrict__ attb)
{
    // 64 KB: K[group][buf][4096] at 0, V[group][buf][4096] at 16384
    __shared__ __align__(16) bh SMEM[32768];

    const int t = threadIdx.x;
    const int wave = t >> 6, lane = t & 63;
    const int group = wave >> 2, w4 = wave & 3;
    const int quad = lane >> 4, c16 = lane & 15;
    const int bh_idx = blockIdx.y;
    const int q0 = blockIdx.x * 128;

    const bh* Qp  = Qb + (size_t)bh_idx * NL * NDH;
    const bh* KVp = KVf + (size_t)bh_idx * 64 * KVBLK;

    bh* Kb = &SMEM[group * 8192];            // [2][4096]
    bh* Vb = &SMEM[16384 + group * 8192];    // [2][4096]

    bf16x8 qf[2][2];
    #pragma unroll
    for (int fq = 0; fq < 2; fq++)
        #pragma unroll
        for (int kc = 0; kc < 2; kc++)
            qf[fq][kc] = *(const bf16x8*)
                &Qp[(size_t)(q0 + w4 * 32 + fq * 16 + c16) * NDH + kc * 32 + quad * 8];

    f32x4 ot[4][2];
    float lsum[2] = {0.0f, 0.0f};
    for (int a = 0; a < 4; a++)
        for (int fq = 0; fq < 2; fq++)
            for (int u = 0; u < 4; u++) ot[a][fq][u] = 0.0f;
    const f32x4 z4 = {0.0f, 0.0f, 0.0f, 0.0f};

    s16x4 pfA[4][2], pfB[4][2];

    auto stageK = [&](int i) {               // K(i) -> Kb[i&1]
        int kt = 2 * i + group;
        const bh* src = KVp + (size_t)kt * KVBLK;
        bh* dst = Kb + (i & 1) * 4096;
        #pragma unroll
        for (int r = 0; r < 2; r++) {
            int off = (w4 * 2 + r) * 512 + lane * 8;
            gload16(src + off, dst + off);
        }
    };
    auto stageV = [&](int i) {               // V(i) -> Vb[i&1]
        int kt = 2 * i + group;
        const bh* src = KVp + (size_t)kt * KVBLK + 4096;
        bh* dst = Vb + (i & 1) * 4096;
        #pragma unroll
        for (int r = 0; r < 2; r++) {
            int off = (w4 * 2 + r) * 512 + lane * 8;
            gload16(src + off, dst + off);
        }
    };

    // body(i): QK(i), PV(i-1) (if doPV), exp(i) -> pfC.  pfP = iter i-1 frags.
    auto body = [&](int i, s16x4 (&pfC)[4][2], s16x4 (&pfP)[4][2],
                    bool doPV, bool last) {
        __syncthreads();                     // K(i), V(i-1) landed; read bufs free
        if (!last) stageK(i + 1);
        stageV(i);
        const bh* sfK = Kb + (i & 1) * 4096;
        const bh* sfV = Vb + ((i + 1) & 1) * 4096;   // == (i-1)&1
        __builtin_amdgcn_s_setprio(1);
        float rs0 = 0.0f, rs1 = 0.0f;
        #pragma unroll
        for (int fk = 0; fk < 4; fk++) {
            // S^T chunk fk = K Q^T (kc=0 consumes zero-C operand)
            bf16x8 kf0 = *(const bf16x8*)&sfK[(fk * 2 + 0) * 512 + lane * 8];
            bf16x8 kf1 = *(const bf16x8*)&sfK[(fk * 2 + 1) * 512 + lane * 8];
            f32x4 s0 = mfma_bf16(kf0, qf[0][0], z4);
            f32x4 s1 = mfma_bf16(kf0, qf[1][0], z4);
            s0 = mfma_bf16(kf1, qf[0][1], s0);
            s1 = mfma_bf16(kf1, qf[1][1], s1);
            // PV(i-1) chunk fk: independent of s0/s1 -> fills MFMA pipe while
            // exp below runs on VALU.
            if (doPV) {
                #pragma unroll
                for (int fn = 0; fn < 4; fn++) {
                    s16x4 vt = *(const s16x4*)&sfV[(fn * 4 + fk) * 256 + lane * 4];
                    ot[fn][0] = mfma16(vt, pfP[fk][0], ot[fn][0]);
                    ot[fn][1] = mfma16(vt, pfP[fk][1], ot[fn][1]);
                }
            }
            float a0 = __builtin_amdgcn_exp2f(s0[0]);
            float a1 = __builtin_amdgcn_exp2f(s0[1]);
            float a2 = __builtin_amdgcn_exp2f(s0[2]);
            float a3 = __builtin_amdgcn_exp2f(s0[3]);
            rs0 += (a0 + a1) + (a2 + a3);
            pfC[fk][0] = pk_bf4(a0, a1, a2, a3);
            float b0 = __builtin_amdgcn_exp2f(s1[0]);
            float b1 = __builtin_amdgcn_exp2f(s1[1]);
            float b2 = __builtin_amdgcn_exp2f(s1[2]);
            float b3 = __builtin_amdgcn_exp2f(s1[3]);
            rs1 += (b0 + b1) + (b2 + b3);
            pfC[fk][1] = pk_bf4(b0, b1, b2, b3);
        }
        lsum[0] += rs0;
        lsum[1] += rs1;
        __builtin_amdgcn_s_setprio(0);
    };

    stageK(0);
    body(0, pfA, pfB, false, false);
    for (int i = 1; i < 31; i += 2) {
        body(i,     pfB, pfA, true, false);
        body(i + 1, pfA, pfB, true, false);
    }
    body(31, pfB, pfA, true, true);

    // ---- tail: PV(31) (V(31) staged in body(31) -> Vb[1])
    __syncthreads();
    {
        const bh* sfV = Vb + 4096;
        __builtin_amdgcn_s_setprio(1);
        #pragma unroll
        for (int fk = 0; fk < 4; fk++)
            #pragma unroll
            for (int fn = 0; fn < 4; fn++) {
                s16x4 vt = *(const s16x4*)&sfV[(fn * 4 + fk) * 256 + lane * 4];
                ot[fn][0] = mfma16(vt, pfB[fk][0], ot[fn][0]);
                ot[fn][1] = mfma16(vt, pfB[fk][1], ot[fn][1]);
            }
        __builtin_amdgcn_s_setprio(0);
    }

    #pragma unroll
    for (int fq = 0; fq < 2; fq++) {
        lsum[fq] += __shfl_xor(lsum[fq], 16);
        lsum[fq] += __shfl_xor(lsum[fq], 32);
    }

    // ---- split-K combine + A-frag scatter epilogue (unchanged layout).
    float* Ocmb = (float*)&SMEM[0];
    float* Lcmb = Ocmb + 128 * 64;
    __syncthreads();
    if (group == 1) {
        #pragma unroll
        for (int fq = 0; fq < 2; fq++) {
            int q = w4 * 32 + fq * 16 + c16;
            #pragma unroll
            for (int fn = 0; fn < 4; fn++)
                *(f32x4*)&Ocmb[q * 64 + fn * 16 + quad * 4] = ot[fn][fq];
            if (quad == 0) Lcmb[q] = lsum[fq];
        }
    }
    __syncthreads();
    if (group == 0) {
        const int b = bh_idx >> 3, h = bh_idx & 7;
        const int mbase16 = (b * NL + q0) >> 4;          // global row / 16 base
        #pragma unroll
        for (int fq = 0; fq < 2; fq++) {
            int q = w4 * 32 + fq * 16 + c16;
            float inv = 1.0f / (lsum[fq] + Lcmb[q]);
            int m16 = mbase16 + w4 * 2 + fq;
            #pragma unroll
            for (int fn = 0; fn < 4; fn++) {
                f32x4 o2 = *(const f32x4*)&Ocmb[q * 64 + fn * 16 + quad * 4];
                size_t addr = ((size_t)m16 * 16 + h * 2 + (fn >> 1)) * 512
                            + (size_t)(((fn & 1) * 2 + (quad >> 1)) * 16 + c16) * 8
                            + (quad & 1) * 4;
                st_bf4(&attb[addr],
                       (ot[fn][fq][0] + o2[0]) * inv, (ot[fn][fq][1] + o2[1]) * inv,
                       (ot[fn][fq][2] + o2[2]) * inv, (ot[fn][fq][3] + o2[3]) * inv);
            }
        }
    }
}

// ---------------------------------------------------------------------------
// Kernel 3: out = att(A-frag) @ Wo (pre-packed) + bo -> fp32 [B,L,C] (unchanged).
// ---------------------------------------------------------------------------
__global__ __launch_bounds__(256, 2)
void out_gemm(const bh* __restrict__ Af, const bh* __restrict__ Wf,
              const float* __restrict__ bo, float* __restrict__ out)
{
    __shared__ __align__(16) bh smem[2][12288];  // per buf: Xl 8192 + Wl 4096 (48 KB)

    const int t = threadIdx.x;
    const int wave = t >> 6, lane = t & 63;
    const int quad = lane >> 4, c16 = lane & 15;
    const int m0 = blockIdx.x * 128;
    const int nt = blockIdx.y;
    const int n0 = nt * 64;
    const int m16b = m0 >> 4;

    f32x4 acc[2][4];
    for (int a = 0; a < 2; a++)
        for (int b = 0; b < 4; b++)
            for (int u = 0; u < 4; u++) acc[a][b][u] = 0.0f;

    auto stage = [&](int k0i, int buf) {
        bh* Xl = &smem[buf][0];
        bh* Wl = &smem[buf][8192];
        #pragma unroll
        for (int r = 0; r < 4; r++) {
            int f = wave * 4 + r;
            const bh* src = Af + ((size_t)(m16b + (f >> 1)) * 16 + k0i * 2 + (f & 1)) * 512
                          + lane * 8;
            gload16(src, &Xl[f * 512 + lane * 8]);
        }
        const bh* wz = Wf + (((size_t)3 * 8 + nt) * 8 + k0i) * 4096;
        #pragma unroll
        for (int r = 0; r < 2; r++) {
            int off = (wave * 2 + r) * 512 + lane * 8;
            gload16(wz + off, &Wl[off]);
        }
    };

    stage(0, 0);
    for (int k0i = 0; k0i < 8; k0i++) {
        const int buf = k0i & 1;
        __syncthreads();
        if (k0i < 7) stage(k0i + 1, buf ^ 1);
        const bh* Xl = &smem[buf][0];
        const bh* Wl = &smem[buf][8192];
        #pragma unroll
        for (int kc = 0; kc < 2; kc++) {
            bf16x8 af0 = *(const bf16x8*)&Xl[((wave * 2 + 0) * 2 + kc) * 512 + lane * 8];
            bf16x8 af1 = *(const bf16x8*)&Xl[((wave * 2 + 1) * 2 + kc) * 512 + lane * 8];
            #pragma unroll
            for (int fn = 0; fn < 4; fn++) {
                bf16x8 bf = *(const bf16x8*)&Wl[(kc * 4 + fn) * 512 + lane * 8];
                acc[0][fn] = mfma_bf16(af0, bf, acc[0][fn]);
                acc[1][fn] = mfma_bf16(af1, bf, acc[1][fn]);
            }
        }
        __syncthreads();
    }

    #pragma unroll
    for (int fm = 0; fm < 2; fm++)
        #pragma unroll
        for (int i = 0; i < 4; i++) {
            int mr = m0 + wave * 32 + fm * 16 + quad * 4 + i;
            #pragma unroll
            for (int fn = 0; fn < 4; fn++) {
                int cn = n0 + fn * 16 + c16;
                out[(size_t)mr * 512 + cn] = acc[fm][fn][i] + bo[cn];
            }
        }
}

// ---------------------------------------------------------------------------
extern "C" void kernel_launch(void* const* d_in, const int* in_sizes, int n_in,
                              void* d_out, int out_size, void* d_ws, size_t ws_size,
                              hipStream_t stream)
{
    const float* x  = (const float*)d_in[0];
    const float* Wq = (const float*)d_in[1];
    const float* Wk = (const float*)d_in[2];
    const float* Wv = (const float*)d_in[3];
    const float* Wo = (const float*)d_in[4];
    const float* bo = (const float*)d_in[5];
    float* out = (float*)d_out;

    const size_t mat = (size_t)NM * NC;       // 4 Mi elems (8 MB bf16)
    bh* Qb   = (bh*)d_ws;                     //  8 MB
    bh* KVf  = Qb + mat;                      // 16 MB
    bh* attb = KVf + 2 * mat;                 //  8 MB (A-frag layout)
    bh* Wf   = attb + mat;                    //  2 MB
    bh* xf   = Wf + 4 * 8 * 8 * 4096;         //  8 MB

    prep      <<<dim3(128, 1, 9),         256, 0, stream>>>(x, Wq, Wk, Wv, Wo, xf, Wf);
    qkv_gemm  <<<dim3(NM / 128, NC / 64), 256, 0, stream>>>(xf, Wf, Qb, KVf);
    flash_attn<<<dim3(NL / 128, NB * NH), 512, 0, stream>>>(Qb, KVf, attb);
    out_gemm  <<<dim3(NM / 128, NC / 64), 256, 0, stream>>>(attb, Wf, bo, out);
}

// Round 2
// 218.703 us; speedup vs baseline: 1.0864x; 1.0864x over previous
//
#include <hip/hip_runtime.h>
#include <hip/hip_bf16.h>

typedef __hip_bfloat16 bh;
typedef __attribute__((ext_vector_type(8))) __bf16 bf16x8;
typedef __attribute__((ext_vector_type(4))) float f32x4;
typedef __attribute__((ext_vector_type(4))) int i32x4;
typedef __attribute__((ext_vector_type(4))) short s16x4;

#define NB 2
#define NL 4096
#define NC 512
#define NH 8
#define NDH 64
#define NM (NB * NL)          // 8192
#define LOG2E 1.4426950408889634f
#define KVBLK 8192            // elems per (bh,kt): 8KB K frags + 8KB V frags

static __device__ __forceinline__ f32x4 mfma_bf16(bf16x8 a, bf16x8 b, f32x4 c) {
    return __builtin_amdgcn_mfma_f32_16x16x32_bf16(a, b, c, 0, 0, 0);
}
static __device__ __forceinline__ f32x4 mfma16(s16x4 a, s16x4 b, f32x4 c) {
    return __builtin_amdgcn_mfma_f32_16x16x16bf16_1k(a, b, c, 0, 0, 0);
}

static __device__ __forceinline__ void st_bf4(bh* dst, float a, float b, float c, float d) {
    bh tmp[4] = {__float2bfloat16(a), __float2bfloat16(b),
                 __float2bfloat16(c), __float2bfloat16(d)};
    *(s16x4*)dst = *(const s16x4*)tmp;
}
static __device__ __forceinline__ s16x4 pk_bf4(float a, float b, float c, float d) {
    bh tmp[4] = {__float2bfloat16(a), __float2bfloat16(b),
                 __float2bfloat16(c), __float2bfloat16(d)};
    return *(const s16x4*)tmp;
}

static __device__ __forceinline__ void gload16(const bh* g, bh* l) {
    __builtin_amdgcn_global_load_lds(
        (const __attribute__((address_space(1))) void*)g,
        (__attribute__((address_space(3))) void*)l,
        16, 0, 0);
}

// ---------------------------------------------------------------------------
// Kernel 0: combined prep (unchanged from R0).
//  z<8: x fp32 -> xf bf16 A-frag blocks (coalesced, LDS-transposed).
//  z==8: W pack (Wq,Wk,Wv,Wo fp32 -> Wf B-frag blocks).
// ---------------------------------------------------------------------------
__global__ __launch_bounds__(256, 2)
void prep(const float* __restrict__ x,
          const float* __restrict__ Wq, const float* __restrict__ Wk,
          const float* __restrict__ Wv, const float* __restrict__ Wo,
          bh* __restrict__ xf, bh* __restrict__ Wf)
{
    const int t = threadIdx.x;
    const int wave = t >> 6, lane = t & 63;
    const int quad = lane >> 4, c16 = lane & 15;

    if (blockIdx.z < 8) {
        __shared__ __align__(16) bh T[64][72];
        const int m64 = blockIdx.x, k64 = blockIdx.z;
        #pragma unroll
        for (int rep = 0; rep < 4; rep++) {
            int li = t + rep * 256;
            int r = li >> 4, c4 = (li & 15) * 4;
            float4 f = *(const float4*)&x[(size_t)(m64 * 64 + r) * 512 + k64 * 64 + c4];
            st_bf4(&T[r][c4], f.x, f.y, f.z, f.w);
        }
        __syncthreads();
        #pragma unroll
        for (int kcl = 0; kcl < 2; kcl++) {
            i32x4 v = *(const i32x4*)&T[wave * 16 + c16][kcl * 32 + quad * 8];
            size_t addr = ((size_t)(m64 * 4 + wave) * 16 + (k64 * 2 + kcl)) * 512 + lane * 8;
            *(i32x4*)&xf[addr] = v;
        }
    } else {
        if (blockIdx.x >= 64) return;
        int task = blockIdx.x * 4 + wave;
        int z = task >> 6, nt = (task >> 3) & 7, k0i = task & 7;
        const float* W = (z == 0) ? Wq : (z == 1) ? Wk : (z == 2) ? Wv : Wo;
        bh* dst = Wf + (((size_t)z * 8 + nt) * 8 + k0i) * 4096;
        #pragma unroll
        for (int kc = 0; kc < 2; kc++)
            #pragma unroll
            for (int fn = 0; fn < 4; fn++) {
                bh tmp[8];
                #pragma unroll
                for (int j = 0; j < 8; j++)
                    tmp[j] = __float2bfloat16(
                        W[(size_t)(k0i * 64 + kc * 32 + quad * 8 + j) * 512
                          + nt * 64 + fn * 16 + c16]);
                *(i32x4*)&dst[(kc * 4 + fn) * 512 + lane * 8] = *(const i32x4*)tmp;
            }
    }
}

// ---------------------------------------------------------------------------
// Kernel 1: fused QKV projection (unchanged from R0).
// ---------------------------------------------------------------------------
__global__ __launch_bounds__(256, 2)
void qkv_gemm(const bh* __restrict__ xf, const bh* __restrict__ Wf,
              bh* __restrict__ Qb, bh* __restrict__ KVf)
{
    __shared__ __align__(16) bh smem[2][20480];  // per buf: Xl 8192 + Wl 12288 (80 KB)

    const int t = threadIdx.x;
    const int wave = t >> 6, lane = t & 63;
    const int quad = lane >> 4, c16 = lane & 15;
    const int m0 = blockIdx.x * 128;
    const int nt = blockIdx.y;
    const int m16b = m0 >> 4;

    f32x4 acc[3][2][4];
    for (int z = 0; z < 3; z++)
        for (int a = 0; a < 2; a++)
            for (int b = 0; b < 4; b++)
                for (int u = 0; u < 4; u++) acc[z][a][b][u] = 0.0f;

    auto stage = [&](int k0i, int buf) {
        bh* Xl = &smem[buf][0];
        bh* Wl = &smem[buf][8192];
        #pragma unroll
        for (int r = 0; r < 4; r++) {
            int f = wave * 4 + r;             // m16l*2 + kcl
            const bh* src = xf + ((size_t)(m16b + (f >> 1)) * 16 + k0i * 2 + (f & 1)) * 512
                          + lane * 8;
            gload16(src, &Xl[f * 512 + lane * 8]);
        }
        #pragma unroll
        for (int z = 0; z < 3; z++) {
            const bh* wz = Wf + (((size_t)z * 8 + nt) * 8 + k0i) * 4096;
            #pragma unroll
            for (int r = 0; r < 2; r++) {
                int off = (wave * 2 + r) * 512 + lane * 8;
                gload16(wz + off, &Wl[z * 4096 + off]);
            }
        }
    };

    stage(0, 0);
    for (int k0i = 0; k0i < 8; k0i++) {
        const int buf = k0i & 1;
        __syncthreads();                      // loads for k0i landed; buf^1 free
        if (k0i < 7) stage(k0i + 1, buf ^ 1);
        const bh* Xl = &smem[buf][0];
        const bh* Wl = &smem[buf][8192];
        #pragma unroll
        for (int kc = 0; kc < 2; kc++) {
            bf16x8 af0 = *(const bf16x8*)&Xl[((wave * 2 + 0) * 2 + kc) * 512 + lane * 8];
            bf16x8 af1 = *(const bf16x8*)&Xl[((wave * 2 + 1) * 2 + kc) * 512 + lane * 8];
            #pragma unroll
            for (int z = 0; z < 3; z++)
                #pragma unroll
                for (int fn = 0; fn < 4; fn++) {
                    bf16x8 bf = *(const bf16x8*)&Wl[z * 4096 + (kc * 4 + fn) * 512 + lane * 8];
                    acc[z][0][fn] = mfma_bf16(af0, bf, acc[z][0][fn]);
                    acc[z][1][fn] = mfma_bf16(af1, bf, acc[z][1][fn]);
                }
        }
        __syncthreads();
    }

    const int h = nt;
    const int b = m0 >> 12;
    const int l0 = m0 & 4095;
    const int bh_i = b * NH + h;
    const int kt0 = l0 >> 6;

    // ---- Phase Q: LDS transpose, coalesced 16B/lane stores to row-major Qb.
    {
        bh* Tq = &smem[0][0];
        #pragma unroll
        for (int fm = 0; fm < 2; fm++)
            #pragma unroll
            for (int i = 0; i < 4; i++) {
                int ll = wave * 32 + fm * 16 + quad * 4 + i;
                #pragma unroll
                for (int fn = 0; fn < 4; fn++)
                    Tq[ll * 68 + fn * 16 + c16] =
                        __float2bfloat16(acc[0][fm][fn][i] * 0.125f);
            }
        __syncthreads();
        int l = t >> 1, half = t & 1;
        bh* dst = Qb + ((size_t)bh_i * NL + l0 + l) * NDH + half * 32;
        const bh* src = &Tq[l * 68 + half * 32];
        #pragma unroll
        for (int r = 0; r < 4; r++)
            *(i32x4*)(dst + r * 8) = *(const i32x4*)(src + r * 8);
        __syncthreads();
    }

    // ---- Phase K: LDS scatter into KVf frag image (xLOG2E), coalesced copy-out.
    {
        bh* Tk = &smem[0][0];
        #pragma unroll
        for (int fm = 0; fm < 2; fm++)
            #pragma unroll
            for (int i = 0; i < 4; i++) {
                int ll = wave * 32 + fm * 16 + quad * 4 + i;
                int ktl = ll >> 6, l64 = ll & 63;
                int fk = l64 >> 4, c16t = l64 & 15;
                #pragma unroll
                for (int fn = 0; fn < 4; fn++) {
                    int d = fn * 16 + c16;
                    int kc = d >> 5, qt = (d >> 3) & 3, j = d & 7;
                    Tk[ktl * 4096 + (fk * 2 + kc) * 512 + (qt * 16 + c16t) * 8 + j] =
                        __float2bfloat16(acc[1][fm][fn][i] * LOG2E);
                }
            }
        __syncthreads();
        int idx = t * 32;
        int ktl = idx >> 12, wi = idx & 4095;
        bh* dst = KVf + (size_t)(bh_i * 64 + kt0 + ktl) * KVBLK + wi;
        #pragma unroll
        for (int r = 0; r < 4; r++)
            *(i32x4*)(dst + r * 8) = *(const i32x4*)&Tk[idx + r * 8];
    }

    // ---- V: contiguous b64 frag stores (unchanged).
    #pragma unroll
    for (int fm = 0; fm < 2; fm++) {
        int fkv = (wave * 2 + fm) & 3;
        int ktv = kt0 + (wave >> 1);
        #pragma unroll
        for (int fn = 0; fn < 4; fn++) {
            size_t addr = (size_t)(bh_i * 64 + ktv) * KVBLK + 4096
                        + (size_t)(fn * 4 + fkv) * 256 + (quad * 16 + c16) * 4;
            st_bf4(&KVf[addr], acc[2][fm][fn][0], acc[2][fm][fn][1],
                               acc[2][fm][fn][2], acc[2][fm][fn][3]);
        }
    }
}

// ---------------------------------------------------------------------------
// Kernel 2: flash attention — split-K, P-in-register PV.
// v6: deferred-PV pipeline with IN-PLACE P update (fixes v5's spill).
//   Iteration i, per fk slot:
//     QK(i,fk) MFMAs -> s0,s1         (independent of pf)
//     PV(i-1,fk) MFMAs consume pf[fk] (independent of s0,s1 -> overlaps exp)
//     exp/pack(i,fk) -> overwrite pf[fk] in place (WAR, program order)
//   Persistent regs identical to R0 (single pf[4][2]); no lambda array refs.
//   K double-buffered (prefetch +1); V double-buffered at one-iter LAG so
//   V(i-1) survives iteration i.  LDS stays 64 KB -> occupancy unchanged.
// ---------------------------------------------------------------------------
__global__ __launch_bounds__(512, 4)
void flash_attn(const bh* __restrict__ Qb, const bh* __restrict__ KVf,
                bh* __restrict__ attb)
{
    // 64 KB: K[group][buf][4096] at 0, V[group][buf][4096] at 16384
    __shared__ __align__(16) bh SMEM[32768];

    const int t = threadIdx.x;
    const int wave = t >> 6, lane = t & 63;
    const int group = wave >> 2, w4 = wave & 3;
    const int quad = lane >> 4, c16 = lane & 15;
    const int bh_idx = blockIdx.y;
    const int q0 = blockIdx.x * 128;

    const bh* Qp  = Qb + (size_t)bh_idx * NL * NDH;
    const bh* KVp = KVf + (size_t)bh_idx * 64 * KVBLK;

    bh* Kb = &SMEM[group * 8192];            // [2][4096]
    bh* Vb = &SMEM[16384 + group * 8192];    // [2][4096]

    bf16x8 qf[2][2];
    #pragma unroll
    for (int fq = 0; fq < 2; fq++)
        #pragma unroll
        for (int kc = 0; kc < 2; kc++)
            qf[fq][kc] = *(const bf16x8*)
                &Qp[(size_t)(q0 + w4 * 32 + fq * 16 + c16) * NDH + kc * 32 + quad * 8];

    f32x4 ot[4][2];
    float lsum[2] = {0.0f, 0.0f};
    for (int a = 0; a < 4; a++)
        for (int fq = 0; fq < 2; fq++)
            for (int u = 0; u < 4; u++) ot[a][fq][u] = 0.0f;
    const f32x4 z4 = {0.0f, 0.0f, 0.0f, 0.0f};

    s16x4 pf[4][2];                          // single P set, updated in place

    auto stageK = [&](int i) {               // K(i) -> Kb[i&1]
        int kt = 2 * i + group;
        const bh* src = KVp + (size_t)kt * KVBLK;
        bh* dst = Kb + (i & 1) * 4096;
        #pragma unroll
        for (int r = 0; r < 2; r++) {
            int off = (w4 * 2 + r) * 512 + lane * 8;
            gload16(src + off, dst + off);
        }
    };
    auto stageV = [&](int i) {               // V(i) -> Vb[i&1]
        int kt = 2 * i + group;
        const bh* src = KVp + (size_t)kt * KVBLK + 4096;
        bh* dst = Vb + (i & 1) * 4096;
        #pragma unroll
        for (int r = 0; r < 2; r++) {
            int off = (w4 * 2 + r) * 512 + lane * 8;
            gload16(src + off, dst + off);
        }
    };

    // ---- prologue: iteration 0 (no PV)
    stageK(0);
    __syncthreads();                         // K(0) landed
    stageK(1);
    stageV(0);
    {
        const bh* sfK = Kb;                  // buf 0
        __builtin_amdgcn_s_setprio(1);
        float rs0 = 0.0f, rs1 = 0.0f;
        #pragma unroll
        for (int fk = 0; fk < 4; fk++) {
            bf16x8 kf0 = *(const bf16x8*)&sfK[(fk * 2 + 0) * 512 + lane * 8];
            bf16x8 kf1 = *(const bf16x8*)&sfK[(fk * 2 + 1) * 512 + lane * 8];
            f32x4 s0 = mfma_bf16(kf0, qf[0][0], z4);
            f32x4 s1 = mfma_bf16(kf0, qf[1][0], z4);
            s0 = mfma_bf16(kf1, qf[0][1], s0);
            s1 = mfma_bf16(kf1, qf[1][1], s1);
            float a0 = __builtin_amdgcn_exp2f(s0[0]);
            float a1 = __builtin_amdgcn_exp2f(s0[1]);
            float a2 = __builtin_amdgcn_exp2f(s0[2]);
            float a3 = __builtin_amdgcn_exp2f(s0[3]);
            rs0 += (a0 + a1) + (a2 + a3);
            pf[fk][0] = pk_bf4(a0, a1, a2, a3);
            float b0 = __builtin_amdgcn_exp2f(s1[0]);
            float b1 = __builtin_amdgcn_exp2f(s1[1]);
            float b2 = __builtin_amdgcn_exp2f(s1[2]);
            float b3 = __builtin_amdgcn_exp2f(s1[3]);
            rs1 += (b0 + b1) + (b2 + b3);
            pf[fk][1] = pk_bf4(b0, b1, b2, b3);
        }
        lsum[0] += rs0;
        lsum[1] += rs1;
        __builtin_amdgcn_s_setprio(0);
    }

    // ---- main loop: iterations 1..31; PV(i-1) interleaved, in-place pf.
    for (int i = 1; i < 32; i++) {
        __syncthreads();                     // K(i), V(i-1) landed; dead bufs free
        if (i < 31) stageK(i + 1);
        stageV(i);
        const bh* sfK = Kb + (i & 1) * 4096;
        const bh* sfV = Vb + ((i + 1) & 1) * 4096;   // == (i-1)&1
        __builtin_amdgcn_s_setprio(1);
        float rs0 = 0.0f, rs1 = 0.0f;
        #pragma unroll
        for (int fk = 0; fk < 4; fk++) {
            // QK(i, fk)
            bf16x8 kf0 = *(const bf16x8*)&sfK[(fk * 2 + 0) * 512 + lane * 8];
            bf16x8 kf1 = *(const bf16x8*)&sfK[(fk * 2 + 1) * 512 + lane * 8];
            f32x4 s0 = mfma_bf16(kf0, qf[0][0], z4);
            f32x4 s1 = mfma_bf16(kf0, qf[1][0], z4);
            s0 = mfma_bf16(kf1, qf[0][1], s0);
            s1 = mfma_bf16(kf1, qf[1][1], s1);
            // PV(i-1, fk): consumes pf[fk] BEFORE it is overwritten below;
            // independent of s0/s1 -> fills the MFMA pipe during exp.
            #pragma unroll
            for (int fn = 0; fn < 4; fn++) {
                s16x4 vt = *(const s16x4*)&sfV[(fn * 4 + fk) * 256 + lane * 4];
                ot[fn][0] = mfma16(vt, pf[fk][0], ot[fn][0]);
                ot[fn][1] = mfma16(vt, pf[fk][1], ot[fn][1]);
            }
            // exp/pack(i, fk) -> pf[fk] in place
            float a0 = __builtin_amdgcn_exp2f(s0[0]);
            float a1 = __builtin_amdgcn_exp2f(s0[1]);
            float a2 = __builtin_amdgcn_exp2f(s0[2]);
            float a3 = __builtin_amdgcn_exp2f(s0[3]);
            rs0 += (a0 + a1) + (a2 + a3);
            pf[fk][0] = pk_bf4(a0, a1, a2, a3);
            float b0 = __builtin_amdgcn_exp2f(s1[0]);
            float b1 = __builtin_amdgcn_exp2f(s1[1]);
            float b2 = __builtin_amdgcn_exp2f(s1[2]);
            float b3 = __builtin_amdgcn_exp2f(s1[3]);
            rs1 += (b0 + b1) + (b2 + b3);
            pf[fk][1] = pk_bf4(b0, b1, b2, b3);
        }
        lsum[0] += rs0;
        lsum[1] += rs1;
        __builtin_amdgcn_s_setprio(0);
    }

    // ---- tail: PV(31) (V(31) staged in iteration 31 -> Vb[1])
    __syncthreads();
    {
        const bh* sfV = Vb + 4096;
        __builtin_amdgcn_s_setprio(1);
        #pragma unroll
        for (int fk = 0; fk < 4; fk++)
            #pragma unroll
            for (int fn = 0; fn < 4; fn++) {
                s16x4 vt = *(const s16x4*)&sfV[(fn * 4 + fk) * 256 + lane * 4];
                ot[fn][0] = mfma16(vt, pf[fk][0], ot[fn][0]);
                ot[fn][1] = mfma16(vt, pf[fk][1], ot[fn][1]);
            }
        __builtin_amdgcn_s_setprio(0);
    }

    #pragma unroll
    for (int fq = 0; fq < 2; fq++) {
        lsum[fq] += __shfl_xor(lsum[fq], 16);
        lsum[fq] += __shfl_xor(lsum[fq], 32);
    }

    // ---- split-K combine + A-frag scatter epilogue (unchanged layout).
    float* Ocmb = (float*)&SMEM[0];
    float* Lcmb = Ocmb + 128 * 64;
    __syncthreads();
    if (group == 1) {
        #pragma unroll
        for (int fq = 0; fq < 2; fq++) {
            int q = w4 * 32 + fq * 16 + c16;
            #pragma unroll
            for (int fn = 0; fn < 4; fn++)
                *(f32x4*)&Ocmb[q * 64 + fn * 16 + quad * 4] = ot[fn][fq];
            if (quad == 0) Lcmb[q] = lsum[fq];
        }
    }
    __syncthreads();
    if (group == 0) {
        const int b = bh_idx >> 3, h = bh_idx & 7;
        const int mbase16 = (b * NL + q0) >> 4;          // global row / 16 base
        #pragma unroll
        for (int fq = 0; fq < 2; fq++) {
            int q = w4 * 32 + fq * 16 + c16;
            float inv = 1.0f / (lsum[fq] + Lcmb[q]);
            int m16 = mbase16 + w4 * 2 + fq;
            #pragma unroll
            for (int fn = 0; fn < 4; fn++) {
                f32x4 o2 = *(const f32x4*)&Ocmb[q * 64 + fn * 16 + quad * 4];
                size_t addr = ((size_t)m16 * 16 + h * 2 + (fn >> 1)) * 512
                            + (size_t)(((fn & 1) * 2 + (quad >> 1)) * 16 + c16) * 8
                            + (quad & 1) * 4;
                st_bf4(&attb[addr],
                       (ot[fn][fq][0] + o2[0]) * inv, (ot[fn][fq][1] + o2[1]) * inv,
                       (ot[fn][fq][2] + o2[2]) * inv, (ot[fn][fq][3] + o2[3]) * inv);
            }
        }
    }
}

// ---------------------------------------------------------------------------
// Kernel 3: out = att(A-frag) @ Wo (pre-packed) + bo -> fp32 [B,L,C] (unchanged).
// ---------------------------------------------------------------------------
__global__ __launch_bounds__(256, 2)
void out_gemm(const bh* __restrict__ Af, const bh* __restrict__ Wf,
              const float* __restrict__ bo, float* __restrict__ out)
{
    __shared__ __align__(16) bh smem[2][12288];  // per buf: Xl 8192 + Wl 4096 (48 KB)

    const int t = threadIdx.x;
    const int wave = t >> 6, lane = t & 63;
    const int quad = lane >> 4, c16 = lane & 15;
    const int m0 = blockIdx.x * 128;
    const int nt = blockIdx.y;
    const int n0 = nt * 64;
    const int m16b = m0 >> 4;

    f32x4 acc[2][4];
    for (int a = 0; a < 2; a++)
        for (int b = 0; b < 4; b++)
            for (int u = 0; u < 4; u++) acc[a][b][u] = 0.0f;

    auto stage = [&](int k0i, int buf) {
        bh* Xl = &smem[buf][0];
        bh* Wl = &smem[buf][8192];
        #pragma unroll
        for (int r = 0; r < 4; r++) {
            int f = wave * 4 + r;
            const bh* src = Af + ((size_t)(m16b + (f >> 1)) * 16 + k0i * 2 + (f & 1)) * 512
                          + lane * 8;
            gload16(src, &Xl[f * 512 + lane * 8]);
        }
        const bh* wz = Wf + (((size_t)3 * 8 + nt) * 8 + k0i) * 4096;
        #pragma unroll
        for (int r = 0; r < 2; r++) {
            int off = (wave * 2 + r) * 512 + lane * 8;
            gload16(wz + off, &Wl[off]);
        }
    };

    stage(0, 0);
    for (int k0i = 0; k0i < 8; k0i++) {
        const int buf = k0i & 1;
        __syncthreads();
        if (k0i < 7) stage(k0i + 1, buf ^ 1);
        const bh* Xl = &smem[buf][0];
        const bh* Wl = &smem[buf][8192];
        #pragma unroll
        for (int kc = 0; kc < 2; kc++) {
            bf16x8 af0 = *(const bf16x8*)&Xl[((wave * 2 + 0) * 2 + kc) * 512 + lane * 8];
            bf16x8 af1 = *(const bf16x8*)&Xl[((wave * 2 + 1) * 2 + kc) * 512 + lane * 8];
            #pragma unroll
            for (int fn = 0; fn < 4; fn++) {
                bf16x8 bf = *(const bf16x8*)&Wl[(kc * 4 + fn) * 512 + lane * 8];
                acc[0][fn] = mfma_bf16(af0, bf, acc[0][fn]);
                acc[1][fn] = mfma_bf16(af1, bf, acc[1][fn]);
            }
        }
        __syncthreads();
    }

    #pragma unroll
    for (int fm = 0; fm < 2; fm++)
        #pragma unroll
        for (int i = 0; i < 4; i++) {
            int mr = m0 + wave * 32 + fm * 16 + quad * 4 + i;
            #pragma unroll
            for (int fn = 0; fn < 4; fn++) {
                int cn = n0 + fn * 16 + c16;
                out[(size_t)mr * 512 + cn] = acc[fm][fn][i] + bo[cn];
            }
        }
}

// ---------------------------------------------------------------------------
extern "C" void kernel_launch(void* const* d_in, const int* in_sizes, int n_in,
                              void* d_out, int out_size, void* d_ws, size_t ws_size,
                              hipStream_t stream)
{
    const float* x  = (const float*)d_in[0];
    const float* Wq = (const float*)d_in[1];
    const float* Wk = (const float*)d_in[2];
    const float* Wv = (const float*)d_in[3];
    const float* Wo = (const float*)d_in[4];
    const float* bo = (const float*)d_in[5];
    float* out = (float*)d_out;

    const size_t mat = (size_t)NM * NC;       // 4 Mi elems (8 MB bf16)
    bh* Qb   = (bh*)d_ws;                     //  8 MB
    bh* KVf  = Qb + mat;                      // 16 MB
    bh* attb = KVf + 2 * mat;                 //  8 MB (A-frag layout)
    bh* Wf   = attb + mat;                    //  2 MB
    bh* xf   = Wf + 4 * 8 * 8 * 4096;         //  8 MB

    prep      <<<dim3(128, 1, 9),         256, 0, stream>>>(x, Wq, Wk, Wv, Wo, xf, Wf);
    qkv_gemm  <<<dim3(NM / 128, NC / 64), 256, 0, stream>>>(xf, Wf, Qb, KVf);
    flash_attn<<<dim3(NL / 128, NB * NH), 512, 0, stream>>>(Qb, KVf, attb);
    out_gemm  <<<dim3(NM / 128, NC / 64), 256, 0, stream>>>(attb, Wf, bo, out);
}

// Round 3
// 182.315 us; speedup vs baseline: 1.3033x; 1.1996x over previous
//
#include <hip/hip_runtime.h>
#include <hip/hip_bf16.h>

typedef __hip_bfloat16 bh;
typedef __attribute__((ext_vector_type(8))) __bf16 bf16x8;
typedef __attribute__((ext_vector_type(4))) float f32x4;
typedef __attribute__((ext_vector_type(4))) int i32x4;
typedef __attribute__((ext_vector_type(4))) short s16x4;

#define NB 2
#define NL 4096
#define NC 512
#define NH 8
#define NDH 64
#define NM (NB * NL)          // 8192
#define LOG2E 1.4426950408889634f
#define KVBLK 8192            // elems per (bh,kt): 8KB K frags + 8KB V frags

static __device__ __forceinline__ f32x4 mfma_bf16(bf16x8 a, bf16x8 b, f32x4 c) {
    return __builtin_amdgcn_mfma_f32_16x16x32_bf16(a, b, c, 0, 0, 0);
}
static __device__ __forceinline__ f32x4 mfma16(s16x4 a, s16x4 b, f32x4 c) {
    return __builtin_amdgcn_mfma_f32_16x16x16bf16_1k(a, b, c, 0, 0, 0);
}

static __device__ __forceinline__ void st_bf4(bh* dst, float a, float b, float c, float d) {
    bh tmp[4] = {__float2bfloat16(a), __float2bfloat16(b),
                 __float2bfloat16(c), __float2bfloat16(d)};
    *(s16x4*)dst = *(const s16x4*)tmp;
}
static __device__ __forceinline__ s16x4 pk_bf4(float a, float b, float c, float d) {
    bh tmp[4] = {__float2bfloat16(a), __float2bfloat16(b),
                 __float2bfloat16(c), __float2bfloat16(d)};
    return *(const s16x4*)tmp;
}

static __device__ __forceinline__ void gload16(const bh* g, bh* l) {
    __builtin_amdgcn_global_load_lds(
        (const __attribute__((address_space(1))) void*)g,
        (__attribute__((address_space(3))) void*)l,
        16, 0, 0);
}

// ---------------------------------------------------------------------------
// Kernel 0: combined prep (unchanged from R0).
//  z<8: x fp32 -> xf bf16 A-frag blocks (coalesced, LDS-transposed).
//  z==8: W pack (Wq,Wk,Wv,Wo fp32 -> Wf B-frag blocks).
// ---------------------------------------------------------------------------
__global__ __launch_bounds__(256, 2)
void prep(const float* __restrict__ x,
          const float* __restrict__ Wq, const float* __restrict__ Wk,
          const float* __restrict__ Wv, const float* __restrict__ Wo,
          bh* __restrict__ xf, bh* __restrict__ Wf)
{
    const int t = threadIdx.x;
    const int wave = t >> 6, lane = t & 63;
    const int quad = lane >> 4, c16 = lane & 15;

    if (blockIdx.z < 8) {
        __shared__ __align__(16) bh T[64][72];
        const int m64 = blockIdx.x, k64 = blockIdx.z;
        #pragma unroll
        for (int rep = 0; rep < 4; rep++) {
            int li = t + rep * 256;
            int r = li >> 4, c4 = (li & 15) * 4;
            float4 f = *(const float4*)&x[(size_t)(m64 * 64 + r) * 512 + k64 * 64 + c4];
            st_bf4(&T[r][c4], f.x, f.y, f.z, f.w);
        }
        __syncthreads();
        #pragma unroll
        for (int kcl = 0; kcl < 2; kcl++) {
            i32x4 v = *(const i32x4*)&T[wave * 16 + c16][kcl * 32 + quad * 8];
            size_t addr = ((size_t)(m64 * 4 + wave) * 16 + (k64 * 2 + kcl)) * 512 + lane * 8;
            *(i32x4*)&xf[addr] = v;
        }
    } else {
        if (blockIdx.x >= 64) return;
        int task = blockIdx.x * 4 + wave;
        int z = task >> 6, nt = (task >> 3) & 7, k0i = task & 7;
        const float* W = (z == 0) ? Wq : (z == 1) ? Wk : (z == 2) ? Wv : Wo;
        bh* dst = Wf + (((size_t)z * 8 + nt) * 8 + k0i) * 4096;
        #pragma unroll
        for (int kc = 0; kc < 2; kc++)
            #pragma unroll
            for (int fn = 0; fn < 4; fn++) {
                bh tmp[8];
                #pragma unroll
                for (int j = 0; j < 8; j++)
                    tmp[j] = __float2bfloat16(
                        W[(size_t)(k0i * 64 + kc * 32 + quad * 8 + j) * 512
                          + nt * 64 + fn * 16 + c16]);
                *(i32x4*)&dst[(kc * 4 + fn) * 512 + lane * 8] = *(const i32x4*)tmp;
            }
    }
}

// ---------------------------------------------------------------------------
// Kernel 1: fused QKV projection (unchanged from R0).
// ---------------------------------------------------------------------------
__global__ __launch_bounds__(256, 2)
void qkv_gemm(const bh* __restrict__ xf, const bh* __restrict__ Wf,
              bh* __restrict__ Qb, bh* __restrict__ KVf)
{
    __shared__ __align__(16) bh smem[2][20480];  // per buf: Xl 8192 + Wl 12288 (80 KB)

    const int t = threadIdx.x;
    const int wave = t >> 6, lane = t & 63;
    const int quad = lane >> 4, c16 = lane & 15;
    const int m0 = blockIdx.x * 128;
    const int nt = blockIdx.y;
    const int m16b = m0 >> 4;

    f32x4 acc[3][2][4];
    for (int z = 0; z < 3; z++)
        for (int a = 0; a < 2; a++)
            for (int b = 0; b < 4; b++)
                for (int u = 0; u < 4; u++) acc[z][a][b][u] = 0.0f;

    auto stage = [&](int k0i, int buf) {
        bh* Xl = &smem[buf][0];
        bh* Wl = &smem[buf][8192];
        #pragma unroll
        for (int r = 0; r < 4; r++) {
            int f = wave * 4 + r;             // m16l*2 + kcl
            const bh* src = xf + ((size_t)(m16b + (f >> 1)) * 16 + k0i * 2 + (f & 1)) * 512
                          + lane * 8;
            gload16(src, &Xl[f * 512 + lane * 8]);
        }
        #pragma unroll
        for (int z = 0; z < 3; z++) {
            const bh* wz = Wf + (((size_t)z * 8 + nt) * 8 + k0i) * 4096;
            #pragma unroll
            for (int r = 0; r < 2; r++) {
                int off = (wave * 2 + r) * 512 + lane * 8;
                gload16(wz + off, &Wl[z * 4096 + off]);
            }
        }
    };

    stage(0, 0);
    for (int k0i = 0; k0i < 8; k0i++) {
        const int buf = k0i & 1;
        __syncthreads();                      // loads for k0i landed; buf^1 free
        if (k0i < 7) stage(k0i + 1, buf ^ 1);
        const bh* Xl = &smem[buf][0];
        const bh* Wl = &smem[buf][8192];
        #pragma unroll
        for (int kc = 0; kc < 2; kc++) {
            bf16x8 af0 = *(const bf16x8*)&Xl[((wave * 2 + 0) * 2 + kc) * 512 + lane * 8];
            bf16x8 af1 = *(const bf16x8*)&Xl[((wave * 2 + 1) * 2 + kc) * 512 + lane * 8];
            #pragma unroll
            for (int z = 0; z < 3; z++)
                #pragma unroll
                for (int fn = 0; fn < 4; fn++) {
                    bf16x8 bf = *(const bf16x8*)&Wl[z * 4096 + (kc * 4 + fn) * 512 + lane * 8];
                    acc[z][0][fn] = mfma_bf16(af0, bf, acc[z][0][fn]);
                    acc[z][1][fn] = mfma_bf16(af1, bf, acc[z][1][fn]);
                }
        }
        __syncthreads();
    }

    const int h = nt;
    const int b = m0 >> 12;
    const int l0 = m0 & 4095;
    const int bh_i = b * NH + h;
    const int kt0 = l0 >> 6;

    // ---- Phase Q: LDS transpose, coalesced 16B/lane stores to row-major Qb.
    {
        bh* Tq = &smem[0][0];
        #pragma unroll
        for (int fm = 0; fm < 2; fm++)
            #pragma unroll
            for (int i = 0; i < 4; i++) {
                int ll = wave * 32 + fm * 16 + quad * 4 + i;
                #pragma unroll
                for (int fn = 0; fn < 4; fn++)
                    Tq[ll * 68 + fn * 16 + c16] =
                        __float2bfloat16(acc[0][fm][fn][i] * 0.125f);
            }
        __syncthreads();
        int l = t >> 1, half = t & 1;
        bh* dst = Qb + ((size_t)bh_i * NL + l0 + l) * NDH + half * 32;
        const bh* src = &Tq[l * 68 + half * 32];
        #pragma unroll
        for (int r = 0; r < 4; r++)
            *(i32x4*)(dst + r * 8) = *(const i32x4*)(src + r * 8);
        __syncthreads();
    }

    // ---- Phase K: LDS scatter into KVf frag image (xLOG2E), coalesced copy-out.
    {
        bh* Tk = &smem[0][0];
        #pragma unroll
        for (int fm = 0; fm < 2; fm++)
            #pragma unroll
            for (int i = 0; i < 4; i++) {
                int ll = wave * 32 + fm * 16 + quad * 4 + i;
                int ktl = ll >> 6, l64 = ll & 63;
                int fk = l64 >> 4, c16t = l64 & 15;
                #pragma unroll
                for (int fn = 0; fn < 4; fn++) {
                    int d = fn * 16 + c16;
                    int kc = d >> 5, qt = (d >> 3) & 3, j = d & 7;
                    Tk[ktl * 4096 + (fk * 2 + kc) * 512 + (qt * 16 + c16t) * 8 + j] =
                        __float2bfloat16(acc[1][fm][fn][i] * LOG2E);
                }
            }
        __syncthreads();
        int idx = t * 32;
        int ktl = idx >> 12, wi = idx & 4095;
        bh* dst = KVf + (size_t)(bh_i * 64 + kt0 + ktl) * KVBLK + wi;
        #pragma unroll
        for (int r = 0; r < 4; r++)
            *(i32x4*)(dst + r * 8) = *(const i32x4*)&Tk[idx + r * 8];
    }

    // ---- V: contiguous b64 frag stores (unchanged).
    #pragma unroll
    for (int fm = 0; fm < 2; fm++) {
        int fkv = (wave * 2 + fm) & 3;
        int ktv = kt0 + (wave >> 1);
        #pragma unroll
        for (int fn = 0; fn < 4; fn++) {
            size_t addr = (size_t)(bh_i * 64 + ktv) * KVBLK + 4096
                        + (size_t)(fn * 4 + fkv) * 256 + (quad * 16 + c16) * 4;
            st_bf4(&KVf[addr], acc[2][fm][fn][0], acc[2][fm][fn][1],
                               acc[2][fm][fn][2], acc[2][fm][fn][3]);
        }
    }
}

// ---------------------------------------------------------------------------
// Kernel 2: flash attention — split-K, P-in-register PV.
// v7: R0 structure restored EXACTLY (staging, LDS layout, single barrier,
// epilogue).  Two register-safe deltas:
//  (a) per-fk tail interleave: exp/pack(fk) immediately followed by PV(fk)
//      (same-iteration V, transient p0/p1) so PV(fk) MFMA can issue under
//      exp(fk+1) VALU; s[fk] dies earlier than in R0 -> pressure <= R0.
//  (b) s_setprio(1) around the compute region (T5).
// ---------------------------------------------------------------------------
__global__ __launch_bounds__(512, 4)
void flash_attn(const bh* __restrict__ Qb, const bh* __restrict__ KVf,
                bh* __restrict__ attb)
{
    __shared__ __align__(16) bh SF[2][2][KVBLK];   // [group][buf], 64 KB

    const int t = threadIdx.x;
    const int wave = t >> 6, lane = t & 63;
    const int group = wave >> 2, w4 = wave & 3;
    const int quad = lane >> 4, c16 = lane & 15;
    const int bh_idx = blockIdx.y;
    const int q0 = blockIdx.x * 128;

    const bh* Qp  = Qb + (size_t)bh_idx * NL * NDH;
    const bh* KVp = KVf + (size_t)bh_idx * 64 * KVBLK;

    bf16x8 qf[2][2];
    #pragma unroll
    for (int fq = 0; fq < 2; fq++)
        #pragma unroll
        for (int kc = 0; kc < 2; kc++)
            qf[fq][kc] = *(const bf16x8*)
                &Qp[(size_t)(q0 + w4 * 32 + fq * 16 + c16) * NDH + kc * 32 + quad * 8];

    f32x4 ot[4][2];
    float lsum[2] = {0.0f, 0.0f};
    for (int a = 0; a < 4; a++)
        for (int fq = 0; fq < 2; fq++)
            for (int u = 0; u < 4; u++) ot[a][fq][u] = 0.0f;
    const f32x4 z4 = {0.0f, 0.0f, 0.0f, 0.0f};

    auto stage = [&](int i, int buf) {
        int kt = 2 * i + group;
        #pragma unroll
        for (int r = 0; r < 4; r++) {
            int off = (w4 * 4 + r) * 512 + lane * 8;
            gload16(KVp + (size_t)kt * KVBLK + off, &SF[group][buf][off]);
        }
    };

    stage(0, 0);
    for (int i = 0; i < 32; i++) {
        const int buf = i & 1;
        __syncthreads();
        if (i < 31) stage(i + 1, buf ^ 1);
        const bh* sf = &SF[group][buf][0];

        __builtin_amdgcn_s_setprio(1);

        // S^T = K Q^T; kc=0 consumes the zero-C operand directly
        f32x4 s[4][2];
        #pragma unroll
        for (int fk = 0; fk < 4; fk++) {
            bf16x8 kf0 = *(const bf16x8*)&sf[(fk * 2 + 0) * 512 + lane * 8];
            s[fk][0] = mfma_bf16(kf0, qf[0][0], z4);
            s[fk][1] = mfma_bf16(kf0, qf[1][0], z4);
        }
        #pragma unroll
        for (int fk = 0; fk < 4; fk++) {
            bf16x8 kf1 = *(const bf16x8*)&sf[(fk * 2 + 1) * 512 + lane * 8];
            s[fk][0] = mfma_bf16(kf1, qf[0][1], s[fk][0]);
            s[fk][1] = mfma_bf16(kf1, qf[1][1], s[fk][1]);
        }

        s16x4 vt[4][4];
        #pragma unroll
        for (int fn = 0; fn < 4; fn++)
            #pragma unroll
            for (int fk = 0; fk < 4; fk++)
                vt[fn][fk] = *(const s16x4*)&sf[4096 + (fn * 4 + fk) * 256 + lane * 4];

        // per-fk: exp/pack then PV immediately (transient p0/p1, no pf array)
        float rs0 = 0.0f, rs1 = 0.0f;
        #pragma unroll
        for (int fk = 0; fk < 4; fk++) {
            float a0 = __builtin_amdgcn_exp2f(s[fk][0][0]);
            float a1 = __builtin_amdgcn_exp2f(s[fk][0][1]);
            float a2 = __builtin_amdgcn_exp2f(s[fk][0][2]);
            float a3 = __builtin_amdgcn_exp2f(s[fk][0][3]);
            rs0 += (a0 + a1) + (a2 + a3);
            s16x4 p0 = pk_bf4(a0, a1, a2, a3);
            float b0 = __builtin_amdgcn_exp2f(s[fk][1][0]);
            float b1 = __builtin_amdgcn_exp2f(s[fk][1][1]);
            float b2 = __builtin_amdgcn_exp2f(s[fk][1][2]);
            float b3 = __builtin_amdgcn_exp2f(s[fk][1][3]);
            rs1 += (b0 + b1) + (b2 + b3);
            s16x4 p1 = pk_bf4(b0, b1, b2, b3);
            #pragma unroll
            for (int fn = 0; fn < 4; fn++) {
                ot[fn][0] = mfma16(vt[fn][fk], p0, ot[fn][0]);
                ot[fn][1] = mfma16(vt[fn][fk], p1, ot[fn][1]);
            }
        }
        lsum[0] += rs0;
        lsum[1] += rs1;

        __builtin_amdgcn_s_setprio(0);
    }

    #pragma unroll
    for (int fq = 0; fq < 2; fq++) {
        lsum[fq] += __shfl_xor(lsum[fq], 16);
        lsum[fq] += __shfl_xor(lsum[fq], 32);
    }

    float* Ocmb = (float*)&SF[0][0][0];
    float* Lcmb = Ocmb + 128 * 64;
    __syncthreads();
    if (group == 1) {
        #pragma unroll
        for (int fq = 0; fq < 2; fq++) {
            int q = w4 * 32 + fq * 16 + c16;
            #pragma unroll
            for (int fn = 0; fn < 4; fn++)
                *(f32x4*)&Ocmb[q * 64 + fn * 16 + quad * 4] = ot[fn][fq];
            if (quad == 0) Lcmb[q] = lsum[fq];
        }
    }
    __syncthreads();
    if (group == 0) {
        const int b = bh_idx >> 3, h = bh_idx & 7;
        const int mbase16 = (b * NL + q0) >> 4;          // global row / 16 base
        #pragma unroll
        for (int fq = 0; fq < 2; fq++) {
            int q = w4 * 32 + fq * 16 + c16;
            float inv = 1.0f / (lsum[fq] + Lcmb[q]);
            int m16 = mbase16 + w4 * 2 + fq;
            #pragma unroll
            for (int fn = 0; fn < 4; fn++) {
                f32x4 o2 = *(const f32x4*)&Ocmb[q * 64 + fn * 16 + quad * 4];
                // A-frag scatter: block (m16, kcg = h*2 + (fn>>1)),
                // elem ((quad'*16 + c16)*8 + j0), quad' = (fn&1)*2 + (quad>>1)
                size_t addr = ((size_t)m16 * 16 + h * 2 + (fn >> 1)) * 512
                            + (size_t)(((fn & 1) * 2 + (quad >> 1)) * 16 + c16) * 8
                            + (quad & 1) * 4;
                st_bf4(&attb[addr],
                       (ot[fn][fq][0] + o2[0]) * inv, (ot[fn][fq][1] + o2[1]) * inv,
                       (ot[fn][fq][2] + o2[2]) * inv, (ot[fn][fq][3] + o2[3]) * inv);
            }
        }
    }
}

// ---------------------------------------------------------------------------
// Kernel 3: out = att(A-frag) @ Wo (pre-packed) + bo -> fp32 [B,L,C] (unchanged).
// ---------------------------------------------------------------------------
__global__ __launch_bounds__(256, 2)
void out_gemm(const bh* __restrict__ Af, const bh* __restrict__ Wf,
              const float* __restrict__ bo, float* __restrict__ out)
{
    __shared__ __align__(16) bh smem[2][12288];  // per buf: Xl 8192 + Wl 4096 (48 KB)

    const int t = threadIdx.x;
    const int wave = t >> 6, lane = t & 63;
    const int quad = lane >> 4, c16 = lane & 15;
    const int m0 = blockIdx.x * 128;
    const int nt = blockIdx.y;
    const int n0 = nt * 64;
    const int m16b = m0 >> 4;

    f32x4 acc[2][4];
    for (int a = 0; a < 2; a++)
        for (int b = 0; b < 4; b++)
            for (int u = 0; u < 4; u++) acc[a][b][u] = 0.0f;

    auto stage = [&](int k0i, int buf) {
        bh* Xl = &smem[buf][0];
        bh* Wl = &smem[buf][8192];
        #pragma unroll
        for (int r = 0; r < 4; r++) {
            int f = wave * 4 + r;
            const bh* src = Af + ((size_t)(m16b + (f >> 1)) * 16 + k0i * 2 + (f & 1)) * 512
                          + lane * 8;
            gload16(src, &Xl[f * 512 + lane * 8]);
        }
        const bh* wz = Wf + (((size_t)3 * 8 + nt) * 8 + k0i) * 4096;
        #pragma unroll
        for (int r = 0; r < 2; r++) {
            int off = (wave * 2 + r) * 512 + lane * 8;
            gload16(wz + off, &Wl[off]);
        }
    };

    stage(0, 0);
    for (int k0i = 0; k0i < 8; k0i++) {
        const int buf = k0i & 1;
        __syncthreads();
        if (k0i < 7) stage(k0i + 1, buf ^ 1);
        const bh* Xl = &smem[buf][0];
        const bh* Wl = &smem[buf][8192];
        #pragma unroll
        for (int kc = 0; kc < 2; kc++) {
            bf16x8 af0 = *(const bf16x8*)&Xl[((wave * 2 + 0) * 2 + kc) * 512 + lane * 8];
            bf16x8 af1 = *(const bf16x8*)&Xl[((wave * 2 + 1) * 2 + kc) * 512 + lane * 8];
            #pragma unroll
            for (int fn = 0; fn < 4; fn++) {
                bf16x8 bf = *(const bf16x8*)&Wl[(kc * 4 + fn) * 512 + lane * 8];
                acc[0][fn] = mfma_bf16(af0, bf, acc[0][fn]);
                acc[1][fn] = mfma_bf16(af1, bf, acc[1][fn]);
            }
        }
        __syncthreads();
    }

    #pragma unroll
    for (int fm = 0; fm < 2; fm++)
        #pragma unroll
        for (int i = 0; i < 4; i++) {
            int mr = m0 + wave * 32 + fm * 16 + quad * 4 + i;
            #pragma unroll
            for (int fn = 0; fn < 4; fn++) {
                int cn = n0 + fn * 16 + c16;
                out[(size_t)mr * 512 + cn] = acc[fm][fn][i] + bo[cn];
            }
        }
}

// ---------------------------------------------------------------------------
extern "C" void kernel_launch(void* const* d_in, const int* in_sizes, int n_in,
                              void* d_out, int out_size, void* d_ws, size_t ws_size,
                              hipStream_t stream)
{
    const float* x  = (const float*)d_in[0];
    const float* Wq = (const float*)d_in[1];
    const float* Wk = (const float*)d_in[2];
    const float* Wv = (const float*)d_in[3];
    const float* Wo = (const float*)d_in[4];
    const float* bo = (const float*)d_in[5];
    float* out = (float*)d_out;

    const size_t mat = (size_t)NM * NC;       // 4 Mi elems (8 MB bf16)
    bh* Qb   = (bh*)d_ws;                     //  8 MB
    bh* KVf  = Qb + mat;                      // 16 MB
    bh* attb = KVf + 2 * mat;                 //  8 MB (A-frag layout)
    bh* Wf   = attb + mat;                    //  2 MB
    bh* xf   = Wf + 4 * 8 * 8 * 4096;         //  8 MB

    prep      <<<dim3(128, 1, 9),         256, 0, stream>>>(x, Wq, Wk, Wv, Wo, xf, Wf);
    qkv_gemm  <<<dim3(NM / 128, NC / 64), 256, 0, stream>>>(xf, Wf, Qb, KVf);
    flash_attn<<<dim3(NL / 128, NB * NH), 512, 0, stream>>>(Qb, KVf, attb);
    out_gemm  <<<dim3(NM / 128, NC / 64), 256, 0, stream>>>(attb, Wf, bo, out);
}

// Round 4
// 178.135 us; speedup vs baseline: 1.3339x; 1.0235x over previous
//
#include <hip/hip_runtime.h>
#include <hip/hip_bf16.h>

typedef __hip_bfloat16 bh;
typedef __attribute__((ext_vector_type(8))) __bf16 bf16x8;
typedef __attribute__((ext_vector_type(4))) float f32x4;
typedef __attribute__((ext_vector_type(4))) int i32x4;
typedef __attribute__((ext_vector_type(4))) short s16x4;

#define NB 2
#define NL 4096
#define NC 512
#define NH 8
#define NDH 64
#define NM (NB * NL)          // 8192
#define LOG2E 1.4426950408889634f
#define KVBLK 8192            // elems per (bh,kt): 8KB K frags + 8KB V frags

static __device__ __forceinline__ f32x4 mfma_bf16(bf16x8 a, bf16x8 b, f32x4 c) {
    return __builtin_amdgcn_mfma_f32_16x16x32_bf16(a, b, c, 0, 0, 0);
}

static __device__ __forceinline__ void st_bf4(bh* dst, float a, float b, float c, float d) {
    bh tmp[4] = {__float2bfloat16(a), __float2bfloat16(b),
                 __float2bfloat16(c), __float2bfloat16(d)};
    *(s16x4*)dst = *(const s16x4*)tmp;
}
static __device__ __forceinline__ bf16x8 pk_bf8(float a0, float a1, float a2, float a3,
                                                float b0, float b1, float b2, float b3) {
    bh tmp[8] = {__float2bfloat16(a0), __float2bfloat16(a1),
                 __float2bfloat16(a2), __float2bfloat16(a3),
                 __float2bfloat16(b0), __float2bfloat16(b1),
                 __float2bfloat16(b2), __float2bfloat16(b3)};
    return *(const bf16x8*)tmp;
}

static __device__ __forceinline__ void gload16(const bh* g, bh* l) {
    __builtin_amdgcn_global_load_lds(
        (const __attribute__((address_space(1))) void*)g,
        (__attribute__((address_space(3))) void*)l,
        16, 0, 0);
}

// ---------------------------------------------------------------------------
// Kernel 0: combined prep (unchanged from R0).
//  z<8: x fp32 -> xf bf16 A-frag blocks (coalesced, LDS-transposed).
//  z==8: W pack (Wq,Wk,Wv,Wo fp32 -> Wf B-frag blocks).
// ---------------------------------------------------------------------------
__global__ __launch_bounds__(256, 2)
void prep(const float* __restrict__ x,
          const float* __restrict__ Wq, const float* __restrict__ Wk,
          const float* __restrict__ Wv, const float* __restrict__ Wo,
          bh* __restrict__ xf, bh* __restrict__ Wf)
{
    const int t = threadIdx.x;
    const int wave = t >> 6, lane = t & 63;
    const int quad = lane >> 4, c16 = lane & 15;

    if (blockIdx.z < 8) {
        __shared__ __align__(16) bh T[64][72];
        const int m64 = blockIdx.x, k64 = blockIdx.z;
        #pragma unroll
        for (int rep = 0; rep < 4; rep++) {
            int li = t + rep * 256;
            int r = li >> 4, c4 = (li & 15) * 4;
            float4 f = *(const float4*)&x[(size_t)(m64 * 64 + r) * 512 + k64 * 64 + c4];
            st_bf4(&T[r][c4], f.x, f.y, f.z, f.w);
        }
        __syncthreads();
        #pragma unroll
        for (int kcl = 0; kcl < 2; kcl++) {
            i32x4 v = *(const i32x4*)&T[wave * 16 + c16][kcl * 32 + quad * 8];
            size_t addr = ((size_t)(m64 * 4 + wave) * 16 + (k64 * 2 + kcl)) * 512 + lane * 8;
            *(i32x4*)&xf[addr] = v;
        }
    } else {
        if (blockIdx.x >= 64) return;
        int task = blockIdx.x * 4 + wave;
        int z = task >> 6, nt = (task >> 3) & 7, k0i = task & 7;
        const float* W = (z == 0) ? Wq : (z == 1) ? Wk : (z == 2) ? Wv : Wo;
        bh* dst = Wf + (((size_t)z * 8 + nt) * 8 + k0i) * 4096;
        #pragma unroll
        for (int kc = 0; kc < 2; kc++)
            #pragma unroll
            for (int fn = 0; fn < 4; fn++) {
                bh tmp[8];
                #pragma unroll
                for (int j = 0; j < 8; j++)
                    tmp[j] = __float2bfloat16(
                        W[(size_t)(k0i * 64 + kc * 32 + quad * 8 + j) * 512
                          + nt * 64 + fn * 16 + c16]);
                *(i32x4*)&dst[(kc * 4 + fn) * 512 + lane * 8] = *(const i32x4*)tmp;
            }
    }
}

// ---------------------------------------------------------------------------
// Kernel 1: fused QKV projection.  Only change vs R0: the V fragment image
// is stored 32-k-interleaved (two adjacent 16-k blocks packed per lane:
// lane*8 + (fkv&1)*4) so flash PV can consume it as a K=32 MFMA A-operand
// with the SAME k-slot permutation as the in-register P packing.
// ---------------------------------------------------------------------------
__global__ __launch_bounds__(256, 2)
void qkv_gemm(const bh* __restrict__ xf, const bh* __restrict__ Wf,
              bh* __restrict__ Qb, bh* __restrict__ KVf)
{
    __shared__ __align__(16) bh smem[2][20480];  // per buf: Xl 8192 + Wl 12288 (80 KB)

    const int t = threadIdx.x;
    const int wave = t >> 6, lane = t & 63;
    const int quad = lane >> 4, c16 = lane & 15;
    const int m0 = blockIdx.x * 128;
    const int nt = blockIdx.y;
    const int m16b = m0 >> 4;

    f32x4 acc[3][2][4];
    for (int z = 0; z < 3; z++)
        for (int a = 0; a < 2; a++)
            for (int b = 0; b < 4; b++)
                for (int u = 0; u < 4; u++) acc[z][a][b][u] = 0.0f;

    auto stage = [&](int k0i, int buf) {
        bh* Xl = &smem[buf][0];
        bh* Wl = &smem[buf][8192];
        #pragma unroll
        for (int r = 0; r < 4; r++) {
            int f = wave * 4 + r;             // m16l*2 + kcl
            const bh* src = xf + ((size_t)(m16b + (f >> 1)) * 16 + k0i * 2 + (f & 1)) * 512
                          + lane * 8;
            gload16(src, &Xl[f * 512 + lane * 8]);
        }
        #pragma unroll
        for (int z = 0; z < 3; z++) {
            const bh* wz = Wf + (((size_t)z * 8 + nt) * 8 + k0i) * 4096;
            #pragma unroll
            for (int r = 0; r < 2; r++) {
                int off = (wave * 2 + r) * 512 + lane * 8;
                gload16(wz + off, &Wl[z * 4096 + off]);
            }
        }
    };

    stage(0, 0);
    for (int k0i = 0; k0i < 8; k0i++) {
        const int buf = k0i & 1;
        __syncthreads();                      // loads for k0i landed; buf^1 free
        if (k0i < 7) stage(k0i + 1, buf ^ 1);
        const bh* Xl = &smem[buf][0];
        const bh* Wl = &smem[buf][8192];
        #pragma unroll
        for (int kc = 0; kc < 2; kc++) {
            bf16x8 af0 = *(const bf16x8*)&Xl[((wave * 2 + 0) * 2 + kc) * 512 + lane * 8];
            bf16x8 af1 = *(const bf16x8*)&Xl[((wave * 2 + 1) * 2 + kc) * 512 + lane * 8];
            #pragma unroll
            for (int z = 0; z < 3; z++)
                #pragma unroll
                for (int fn = 0; fn < 4; fn++) {
                    bf16x8 bf = *(const bf16x8*)&Wl[z * 4096 + (kc * 4 + fn) * 512 + lane * 8];
                    acc[z][0][fn] = mfma_bf16(af0, bf, acc[z][0][fn]);
                    acc[z][1][fn] = mfma_bf16(af1, bf, acc[z][1][fn]);
                }
        }
        __syncthreads();
    }

    const int h = nt;
    const int b = m0 >> 12;
    const int l0 = m0 & 4095;
    const int bh_i = b * NH + h;
    const int kt0 = l0 >> 6;

    // ---- Phase Q: LDS transpose, coalesced 16B/lane stores to row-major Qb.
    {
        bh* Tq = &smem[0][0];
        #pragma unroll
        for (int fm = 0; fm < 2; fm++)
            #pragma unroll
            for (int i = 0; i < 4; i++) {
                int ll = wave * 32 + fm * 16 + quad * 4 + i;
                #pragma unroll
                for (int fn = 0; fn < 4; fn++)
                    Tq[ll * 68 + fn * 16 + c16] =
                        __float2bfloat16(acc[0][fm][fn][i] * 0.125f);
            }
        __syncthreads();
        int l = t >> 1, half = t & 1;
        bh* dst = Qb + ((size_t)bh_i * NL + l0 + l) * NDH + half * 32;
        const bh* src = &Tq[l * 68 + half * 32];
        #pragma unroll
        for (int r = 0; r < 4; r++)
            *(i32x4*)(dst + r * 8) = *(const i32x4*)(src + r * 8);
        __syncthreads();
    }

    // ---- Phase K: LDS scatter into KVf frag image (xLOG2E), coalesced copy-out.
    {
        bh* Tk = &smem[0][0];
        #pragma unroll
        for (int fm = 0; fm < 2; fm++)
            #pragma unroll
            for (int i = 0; i < 4; i++) {
                int ll = wave * 32 + fm * 16 + quad * 4 + i;
                int ktl = ll >> 6, l64 = ll & 63;
                int fk = l64 >> 4, c16t = l64 & 15;
                #pragma unroll
                for (int fn = 0; fn < 4; fn++) {
                    int d = fn * 16 + c16;
                    int kc = d >> 5, qt = (d >> 3) & 3, j = d & 7;
                    Tk[ktl * 4096 + (fk * 2 + kc) * 512 + (qt * 16 + c16t) * 8 + j] =
                        __float2bfloat16(acc[1][fm][fn][i] * LOG2E);
                }
            }
        __syncthreads();
        int idx = t * 32;
        int ktl = idx >> 12, wi = idx & 4095;
        bh* dst = KVf + (size_t)(bh_i * 64 + kt0 + ktl) * KVBLK + wi;
        #pragma unroll
        for (int r = 0; r < 4; r++)
            *(i32x4*)(dst + r * 8) = *(const i32x4*)&Tk[idx + r * 8];
    }

    // ---- V: 32-k interleaved frag stores.  Block (fn, a=fkv>>1) of 512
    // elems; lane slot j<4 <- fkv even (k=32a+quad*4+i), j>=4 <- fkv odd
    // (k=32a+16+quad*4+i).  Matches flash's P packing permutation.
    #pragma unroll
    for (int fm = 0; fm < 2; fm++) {
        int fkv = (wave * 2 + fm) & 3;
        int ktv = kt0 + (wave >> 1);
        #pragma unroll
        for (int fn = 0; fn < 4; fn++) {
            size_t addr = (size_t)(bh_i * 64 + ktv) * KVBLK + 4096
                        + (size_t)(fn * 2 + (fkv >> 1)) * 512 + lane * 8 + (fkv & 1) * 4;
            st_bf4(&KVf[addr], acc[2][fm][fn][0], acc[2][fm][fn][1],
                               acc[2][fm][fn][2], acc[2][fm][fn][3]);
        }
    }
}

// ---------------------------------------------------------------------------
// Kernel 2: flash attention — split-K, P-in-register PV.
// v8: PV upgraded from 32x mfma_16x16x16 to 16x mfma_16x16x32 (K=16 legacy
// MFMA costs the same matrix-pipe time as K=32 -> PV was wasting half the
// pipe).  P is packed 8-wide per lane ({s[2a] x4, s[2a+1] x4}); the V frag
// image was pre-permuted identically in qkv_gemm, so the k-slot permutation
// cancels in the dot product.  V LDS reads: 8x b128 (was 16x b64).
// Structure otherwise identical to R0 (no setprio, same staging/barriers).
// ---------------------------------------------------------------------------
__global__ __launch_bounds__(512, 4)
void flash_attn(const bh* __restrict__ Qb, const bh* __restrict__ KVf,
                bh* __restrict__ attb)
{
    __shared__ __align__(16) bh SF[2][2][KVBLK];   // [group][buf], 64 KB

    const int t = threadIdx.x;
    const int wave = t >> 6, lane = t & 63;
    const int group = wave >> 2, w4 = wave & 3;
    const int quad = lane >> 4, c16 = lane & 15;
    const int bh_idx = blockIdx.y;
    const int q0 = blockIdx.x * 128;

    const bh* Qp  = Qb + (size_t)bh_idx * NL * NDH;
    const bh* KVp = KVf + (size_t)bh_idx * 64 * KVBLK;

    bf16x8 qf[2][2];
    #pragma unroll
    for (int fq = 0; fq < 2; fq++)
        #pragma unroll
        for (int kc = 0; kc < 2; kc++)
            qf[fq][kc] = *(const bf16x8*)
                &Qp[(size_t)(q0 + w4 * 32 + fq * 16 + c16) * NDH + kc * 32 + quad * 8];

    f32x4 ot[4][2];
    float lsum[2] = {0.0f, 0.0f};
    for (int a = 0; a < 4; a++)
        for (int fq = 0; fq < 2; fq++)
            for (int u = 0; u < 4; u++) ot[a][fq][u] = 0.0f;
    const f32x4 z4 = {0.0f, 0.0f, 0.0f, 0.0f};

    auto stage = [&](int i, int buf) {
        int kt = 2 * i + group;
        #pragma unroll
        for (int r = 0; r < 4; r++) {
            int off = (w4 * 4 + r) * 512 + lane * 8;
            gload16(KVp + (size_t)kt * KVBLK + off, &SF[group][buf][off]);
        }
    };

    stage(0, 0);
    for (int i = 0; i < 32; i++) {
        const int buf = i & 1;
        __syncthreads();
        if (i < 31) stage(i + 1, buf ^ 1);
        const bh* sf = &SF[group][buf][0];

        // S^T = K Q^T; kc=0 consumes the zero-C operand directly
        f32x4 s[4][2];
        #pragma unroll
        for (int fk = 0; fk < 4; fk++) {
            bf16x8 kf0 = *(const bf16x8*)&sf[(fk * 2 + 0) * 512 + lane * 8];
            s[fk][0] = mfma_bf16(kf0, qf[0][0], z4);
            s[fk][1] = mfma_bf16(kf0, qf[1][0], z4);
        }
        #pragma unroll
        for (int fk = 0; fk < 4; fk++) {
            bf16x8 kf1 = *(const bf16x8*)&sf[(fk * 2 + 1) * 512 + lane * 8];
            s[fk][0] = mfma_bf16(kf1, qf[0][1], s[fk][0]);
            s[fk][1] = mfma_bf16(kf1, qf[1][1], s[fk][1]);
        }

        // V frags: 8x b128 (32-k interleaved image)
        bf16x8 vt[4][2];
        #pragma unroll
        for (int fn = 0; fn < 4; fn++)
            #pragma unroll
            for (int a = 0; a < 2; a++)
                vt[fn][a] = *(const bf16x8*)&sf[4096 + (fn * 2 + a) * 512 + lane * 8];

        float rs0 = 0.0f, rs1 = 0.0f;
        #pragma unroll
        for (int a = 0; a < 2; a++) {
            float a0 = __builtin_amdgcn_exp2f(s[2 * a][0][0]);
            float a1 = __builtin_amdgcn_exp2f(s[2 * a][0][1]);
            float a2 = __builtin_amdgcn_exp2f(s[2 * a][0][2]);
            float a3 = __builtin_amdgcn_exp2f(s[2 * a][0][3]);
            float a4 = __builtin_amdgcn_exp2f(s[2 * a + 1][0][0]);
            float a5 = __builtin_amdgcn_exp2f(s[2 * a + 1][0][1]);
            float a6 = __builtin_amdgcn_exp2f(s[2 * a + 1][0][2]);
            float a7 = __builtin_amdgcn_exp2f(s[2 * a + 1][0][3]);
            rs0 += ((a0 + a1) + (a2 + a3)) + ((a4 + a5) + (a6 + a7));
            bf16x8 p0 = pk_bf8(a0, a1, a2, a3, a4, a5, a6, a7);
            float b0 = __builtin_amdgcn_exp2f(s[2 * a][1][0]);
            float b1 = __builtin_amdgcn_exp2f(s[2 * a][1][1]);
            float b2 = __builtin_amdgcn_exp2f(s[2 * a][1][2]);
            float b3 = __builtin_amdgcn_exp2f(s[2 * a][1][3]);
            float b4 = __builtin_amdgcn_exp2f(s[2 * a + 1][1][0]);
            float b5 = __builtin_amdgcn_exp2f(s[2 * a + 1][1][1]);
            float b6 = __builtin_amdgcn_exp2f(s[2 * a + 1][1][2]);
            float b7 = __builtin_amdgcn_exp2f(s[2 * a + 1][1][3]);
            rs1 += ((b0 + b1) + (b2 + b3)) + ((b4 + b5) + (b6 + b7));
            bf16x8 p1 = pk_bf8(b0, b1, b2, b3, b4, b5, b6, b7);
            #pragma unroll
            for (int fn = 0; fn < 4; fn++) {
                ot[fn][0] = mfma_bf16(vt[fn][a], p0, ot[fn][0]);
                ot[fn][1] = mfma_bf16(vt[fn][a], p1, ot[fn][1]);
            }
        }
        lsum[0] += rs0;
        lsum[1] += rs1;
    }

    #pragma unroll
    for (int fq = 0; fq < 2; fq++) {
        lsum[fq] += __shfl_xor(lsum[fq], 16);
        lsum[fq] += __shfl_xor(lsum[fq], 32);
    }

    float* Ocmb = (float*)&SF[0][0][0];
    float* Lcmb = Ocmb + 128 * 64;
    __syncthreads();
    if (group == 1) {
        #pragma unroll
        for (int fq = 0; fq < 2; fq++) {
            int q = w4 * 32 + fq * 16 + c16;
            #pragma unroll
            for (int fn = 0; fn < 4; fn++)
                *(f32x4*)&Ocmb[q * 64 + fn * 16 + quad * 4] = ot[fn][fq];
            if (quad == 0) Lcmb[q] = lsum[fq];
        }
    }
    __syncthreads();
    if (group == 0) {
        const int b = bh_idx >> 3, h = bh_idx & 7;
        const int mbase16 = (b * NL + q0) >> 4;          // global row / 16 base
        #pragma unroll
        for (int fq = 0; fq < 2; fq++) {
            int q = w4 * 32 + fq * 16 + c16;
            float inv = 1.0f / (lsum[fq] + Lcmb[q]);
            int m16 = mbase16 + w4 * 2 + fq;
            #pragma unroll
            for (int fn = 0; fn < 4; fn++) {
                f32x4 o2 = *(const f32x4*)&Ocmb[q * 64 + fn * 16 + quad * 4];
                // A-frag scatter: block (m16, kcg = h*2 + (fn>>1)),
                // elem ((quad'*16 + c16)*8 + j0), quad' = (fn&1)*2 + (quad>>1)
                size_t addr = ((size_t)m16 * 16 + h * 2 + (fn >> 1)) * 512
                            + (size_t)(((fn & 1) * 2 + (quad >> 1)) * 16 + c16) * 8
                            + (quad & 1) * 4;
                st_bf4(&attb[addr],
                       (ot[fn][fq][0] + o2[0]) * inv, (ot[fn][fq][1] + o2[1]) * inv,
                       (ot[fn][fq][2] + o2[2]) * inv, (ot[fn][fq][3] + o2[3]) * inv);
            }
        }
    }
}

// ---------------------------------------------------------------------------
// Kernel 3: out = att(A-frag) @ Wo (pre-packed) + bo -> fp32 [B,L,C] (unchanged).
// ---------------------------------------------------------------------------
__global__ __launch_bounds__(256, 2)
void out_gemm(const bh* __restrict__ Af, const bh* __restrict__ Wf,
              const float* __restrict__ bo, float* __restrict__ out)
{
    __shared__ __align__(16) bh smem[2][12288];  // per buf: Xl 8192 + Wl 4096 (48 KB)

    const int t = threadIdx.x;
    const int wave = t >> 6, lane = t & 63;
    const int quad = lane >> 4, c16 = lane & 15;
    const int m0 = blockIdx.x * 128;
    const int nt = blockIdx.y;
    const int n0 = nt * 64;
    const int m16b = m0 >> 4;

    f32x4 acc[2][4];
    for (int a = 0; a < 2; a++)
        for (int b = 0; b < 4; b++)
            for (int u = 0; u < 4; u++) acc[a][b][u] = 0.0f;

    auto stage = [&](int k0i, int buf) {
        bh* Xl = &smem[buf][0];
        bh* Wl = &smem[buf][8192];
        #pragma unroll
        for (int r = 0; r < 4; r++) {
            int f = wave * 4 + r;
            const bh* src = Af + ((size_t)(m16b + (f >> 1)) * 16 + k0i * 2 + (f & 1)) * 512
                          + lane * 8;
            gload16(src, &Xl[f * 512 + lane * 8]);
        }
        const bh* wz = Wf + (((size_t)3 * 8 + nt) * 8 + k0i) * 4096;
        #pragma unroll
        for (int r = 0; r < 2; r++) {
            int off = (wave * 2 + r) * 512 + lane * 8;
            gload16(wz + off, &Wl[off]);
        }
    };

    stage(0, 0);
    for (int k0i = 0; k0i < 8; k0i++) {
        const int buf = k0i & 1;
        __syncthreads();
        if (k0i < 7) stage(k0i + 1, buf ^ 1);
        const bh* Xl = &smem[buf][0];
        const bh* Wl = &smem[buf][8192];
        #pragma unroll
        for (int kc = 0; kc < 2; kc++) {
            bf16x8 af0 = *(const bf16x8*)&Xl[((wave * 2 + 0) * 2 + kc) * 512 + lane * 8];
            bf16x8 af1 = *(const bf16x8*)&Xl[((wave * 2 + 1) * 2 + kc) * 512 + lane * 8];
            #pragma unroll
            for (int fn = 0; fn < 4; fn++) {
                bf16x8 bf = *(const bf16x8*)&Wl[(kc * 4 + fn) * 512 + lane * 8];
                acc[0][fn] = mfma_bf16(af0, bf, acc[0][fn]);
                acc[1][fn] = mfma_bf16(af1, bf, acc[1][fn]);
            }
        }
        __syncthreads();
    }

    #pragma unroll
    for (int fm = 0; fm < 2; fm++)
        #pragma unroll
        for (int i = 0; i < 4; i++) {
            int mr = m0 + wave * 32 + fm * 16 + quad * 4 + i;
            #pragma unroll
            for (int fn = 0; fn < 4; fn++) {
                int cn = n0 + fn * 16 + c16;
                out[(size_t)mr * 512 + cn] = acc[fm][fn][i] + bo[cn];
            }
        }
}

// ---------------------------------------------------------------------------
extern "C" void kernel_launch(void* const* d_in, const int* in_sizes, int n_in,
                              void* d_out, int out_size, void* d_ws, size_t ws_size,
                              hipStream_t stream)
{
    const float* x  = (const float*)d_in[0];
    const float* Wq = (const float*)d_in[1];
    const float* Wk = (const float*)d_in[2];
    const float* Wv = (const float*)d_in[3];
    const float* Wo = (const float*)d_in[4];
    const float* bo = (const float*)d_in[5];
    float* out = (float*)d_out;

    const size_t mat = (size_t)NM * NC;       // 4 Mi elems (8 MB bf16)
    bh* Qb   = (bh*)d_ws;                     //  8 MB
    bh* KVf  = Qb + mat;                      // 16 MB
    bh* attb = KVf + 2 * mat;                 //  8 MB (A-frag layout)
    bh* Wf   = attb + mat;                    //  2 MB
    bh* xf   = Wf + 4 * 8 * 8 * 4096;         //  8 MB

    prep      <<<dim3(128, 1, 9),         256, 0, stream>>>(x, Wq, Wk, Wv, Wo, xf, Wf);
    qkv_gemm  <<<dim3(NM / 128, NC / 64), 256, 0, stream>>>(xf, Wf, Qb, KVf);
    flash_attn<<<dim3(NL / 128, NB * NH), 512, 0, stream>>>(Qb, KVf, attb);
    out_gemm  <<<dim3(NM / 128, NC / 64), 256, 0, stream>>>(attb, Wf, bo, out);
}

// Round 6
// 178.088 us; speedup vs baseline: 1.3342x; 1.0003x over previous
//
#include <hip/hip_runtime.h>
#include <hip/hip_bf16.h>

typedef __hip_bfloat16 bh;
typedef __attribute__((ext_vector_type(8))) __bf16 bf16x8;
typedef __attribute__((ext_vector_type(4))) float f32x4;
typedef __attribute__((ext_vector_type(4))) int i32x4;
typedef __attribute__((ext_vector_type(4))) short s16x4;

#define NB 2
#define NL 4096
#define NC 512
#define NH 8
#define NDH 64
#define NM (NB * NL)          // 8192
#define LOG2E 1.4426950408889634f
#define KVBLK 8192            // elems per (bh,kt): 8KB K frags + 8KB V frags

static __device__ __forceinline__ f32x4 mfma_bf16(bf16x8 a, bf16x8 b, f32x4 c) {
    return __builtin_amdgcn_mfma_f32_16x16x32_bf16(a, b, c, 0, 0, 0);
}

static __device__ __forceinline__ void st_bf4(bh* dst, float a, float b, float c, float d) {
    bh tmp[4] = {__float2bfloat16(a), __float2bfloat16(b),
                 __float2bfloat16(c), __float2bfloat16(d)};
    *(s16x4*)dst = *(const s16x4*)tmp;
}
static __device__ __forceinline__ bf16x8 pk_bf8(float a0, float a1, float a2, float a3,
                                                float b0, float b1, float b2, float b3) {
    bh tmp[8] = {__float2bfloat16(a0), __float2bfloat16(a1),
                 __float2bfloat16(a2), __float2bfloat16(a3),
                 __float2bfloat16(b0), __float2bfloat16(b1),
                 __float2bfloat16(b2), __float2bfloat16(b3)};
    return *(const bf16x8*)tmp;
}

static __device__ __forceinline__ void gload16(const bh* g, bh* l) {
    __builtin_amdgcn_global_load_lds(
        (const __attribute__((address_space(1))) void*)g,
        (__attribute__((address_space(3))) void*)l,
        16, 0, 0);
}

// ---------------------------------------------------------------------------
// Kernel 0: combined prep (unchanged).
//  z<8: x fp32 -> xf bf16 A-frag blocks (coalesced, LDS-transposed).
//  z==8: W pack (Wq,Wk,Wv,Wo fp32 -> Wf B-frag blocks).
// ---------------------------------------------------------------------------
__global__ __launch_bounds__(256, 2)
void prep(const float* __restrict__ x,
          const float* __restrict__ Wq, const float* __restrict__ Wk,
          const float* __restrict__ Wv, const float* __restrict__ Wo,
          bh* __restrict__ xf, bh* __restrict__ Wf)
{
    const int t = threadIdx.x;
    const int wave = t >> 6, lane = t & 63;
    const int quad = lane >> 4, c16 = lane & 15;

    if (blockIdx.z < 8) {
        __shared__ __align__(16) bh T[64][72];
        const int m64 = blockIdx.x, k64 = blockIdx.z;
        #pragma unroll
        for (int rep = 0; rep < 4; rep++) {
            int li = t + rep * 256;
            int r = li >> 4, c4 = (li & 15) * 4;
            float4 f = *(const float4*)&x[(size_t)(m64 * 64 + r) * 512 + k64 * 64 + c4];
            st_bf4(&T[r][c4], f.x, f.y, f.z, f.w);
        }
        __syncthreads();
        #pragma unroll
        for (int kcl = 0; kcl < 2; kcl++) {
            i32x4 v = *(const i32x4*)&T[wave * 16 + c16][kcl * 32 + quad * 8];
            size_t addr = ((size_t)(m64 * 4 + wave) * 16 + (k64 * 2 + kcl)) * 512 + lane * 8;
            *(i32x4*)&xf[addr] = v;
        }
    } else {
        if (blockIdx.x >= 64) return;
        int task = blockIdx.x * 4 + wave;
        int z = task >> 6, nt = (task >> 3) & 7, k0i = task & 7;
        const float* W = (z == 0) ? Wq : (z == 1) ? Wk : (z == 2) ? Wv : Wo;
        bh* dst = Wf + (((size_t)z * 8 + nt) * 8 + k0i) * 4096;
        #pragma unroll
        for (int kc = 0; kc < 2; kc++)
            #pragma unroll
            for (int fn = 0; fn < 4; fn++) {
                bh tmp[8];
                #pragma unroll
                for (int j = 0; j < 8; j++)
                    tmp[j] = __float2bfloat16(
                        W[(size_t)(k0i * 64 + kc * 32 + quad * 8 + j) * 512
                          + nt * 64 + fn * 16 + c16]);
                *(i32x4*)&dst[(kc * 4 + fn) * 512 + lane * 8] = *(const i32x4*)tmp;
            }
    }
}

// ---------------------------------------------------------------------------
// Kernel 1: fused QKV projection (unchanged from R4: V frag image stored
// 32-k-interleaved to match flash's P packing permutation).
// ---------------------------------------------------------------------------
__global__ __launch_bounds__(256, 2)
void qkv_gemm(const bh* __restrict__ xf, const bh* __restrict__ Wf,
              bh* __restrict__ Qb, bh* __restrict__ KVf)
{
    __shared__ __align__(16) bh smem[2][20480];  // per buf: Xl 8192 + Wl 12288 (80 KB)

    const int t = threadIdx.x;
    const int wave = t >> 6, lane = t & 63;
    const int quad = lane >> 4, c16 = lane & 15;
    const int m0 = blockIdx.x * 128;
    const int nt = blockIdx.y;
    const int m16b = m0 >> 4;

    f32x4 acc[3][2][4];
    for (int z = 0; z < 3; z++)
        for (int a = 0; a < 2; a++)
            for (int b = 0; b < 4; b++)
                for (int u = 0; u < 4; u++) acc[z][a][b][u] = 0.0f;

    auto stage = [&](int k0i, int buf) {
        bh* Xl = &smem[buf][0];
        bh* Wl = &smem[buf][8192];
        #pragma unroll
        for (int r = 0; r < 4; r++) {
            int f = wave * 4 + r;             // m16l*2 + kcl
            const bh* src = xf + ((size_t)(m16b + (f >> 1)) * 16 + k0i * 2 + (f & 1)) * 512
                          + lane * 8;
            gload16(src, &Xl[f * 512 + lane * 8]);
        }
        #pragma unroll
        for (int z = 0; z < 3; z++) {
            const bh* wz = Wf + (((size_t)z * 8 + nt) * 8 + k0i) * 4096;
            #pragma unroll
            for (int r = 0; r < 2; r++) {
                int off = (wave * 2 + r) * 512 + lane * 8;
                gload16(wz + off, &Wl[z * 4096 + off]);
            }
        }
    };

    stage(0, 0);
    for (int k0i = 0; k0i < 8; k0i++) {
        const int buf = k0i & 1;
        __syncthreads();                      // loads for k0i landed; buf^1 free
        if (k0i < 7) stage(k0i + 1, buf ^ 1);
        const bh* Xl = &smem[buf][0];
        const bh* Wl = &smem[buf][8192];
        #pragma unroll
        for (int kc = 0; kc < 2; kc++) {
            bf16x8 af0 = *(const bf16x8*)&Xl[((wave * 2 + 0) * 2 + kc) * 512 + lane * 8];
            bf16x8 af1 = *(const bf16x8*)&Xl[((wave * 2 + 1) * 2 + kc) * 512 + lane * 8];
            #pragma unroll
            for (int z = 0; z < 3; z++)
                #pragma unroll
                for (int fn = 0; fn < 4; fn++) {
                    bf16x8 bf = *(const bf16x8*)&Wl[z * 4096 + (kc * 4 + fn) * 512 + lane * 8];
                    acc[z][0][fn] = mfma_bf16(af0, bf, acc[z][0][fn]);
                    acc[z][1][fn] = mfma_bf16(af1, bf, acc[z][1][fn]);
                }
        }
        __syncthreads();
    }

    const int h = nt;
    const int b = m0 >> 12;
    const int l0 = m0 & 4095;
    const int bh_i = b * NH + h;
    const int kt0 = l0 >> 6;

    // ---- Phase Q: LDS transpose, coalesced 16B/lane stores to row-major Qb.
    {
        bh* Tq = &smem[0][0];
        #pragma unroll
        for (int fm = 0; fm < 2; fm++)
            #pragma unroll
            for (int i = 0; i < 4; i++) {
                int ll = wave * 32 + fm * 16 + quad * 4 + i;
                #pragma unroll
                for (int fn = 0; fn < 4; fn++)
                    Tq[ll * 68 + fn * 16 + c16] =
                        __float2bfloat16(acc[0][fm][fn][i] * 0.125f);
            }
        __syncthreads();
        int l = t >> 1, half = t & 1;
        bh* dst = Qb + ((size_t)bh_i * NL + l0 + l) * NDH + half * 32;
        const bh* src = &Tq[l * 68 + half * 32];
        #pragma unroll
        for (int r = 0; r < 4; r++)
            *(i32x4*)(dst + r * 8) = *(const i32x4*)(src + r * 8);
        __syncthreads();
    }

    // ---- Phase K: LDS scatter into KVf frag image (xLOG2E), coalesced copy-out.
    {
        bh* Tk = &smem[0][0];
        #pragma unroll
        for (int fm = 0; fm < 2; fm++)
            #pragma unroll
            for (int i = 0; i < 4; i++) {
                int ll = wave * 32 + fm * 16 + quad * 4 + i;
                int ktl = ll >> 6, l64 = ll & 63;
                int fk = l64 >> 4, c16t = l64 & 15;
                #pragma unroll
                for (int fn = 0; fn < 4; fn++) {
                    int d = fn * 16 + c16;
                    int kc = d >> 5, qt = (d >> 3) & 3, j = d & 7;
                    Tk[ktl * 4096 + (fk * 2 + kc) * 512 + (qt * 16 + c16t) * 8 + j] =
                        __float2bfloat16(acc[1][fm][fn][i] * LOG2E);
                }
            }
        __syncthreads();
        int idx = t * 32;
        int ktl = idx >> 12, wi = idx & 4095;
        bh* dst = KVf + (size_t)(bh_i * 64 + kt0 + ktl) * KVBLK + wi;
        #pragma unroll
        for (int r = 0; r < 4; r++)
            *(i32x4*)(dst + r * 8) = *(const i32x4*)&Tk[idx + r * 8];
    }

    // ---- V: 32-k interleaved frag stores (R4 layout).
    #pragma unroll
    for (int fm = 0; fm < 2; fm++) {
        int fkv = (wave * 2 + fm) & 3;
        int ktv = kt0 + (wave >> 1);
        #pragma unroll
        for (int fn = 0; fn < 4; fn++) {
            size_t addr = (size_t)(bh_i * 64 + ktv) * KVBLK + 4096
                        + (size_t)(fn * 2 + (fkv >> 1)) * 512 + lane * 8 + (fkv & 1) * 4;
            st_bf4(&KVf[addr], acc[2][fm][fn][0], acc[2][fm][fn][1],
                               acc[2][fm][fn][2], acc[2][fm][fn][3]);
        }
    }
}

// ---------------------------------------------------------------------------
// Kernel 2: flash attention — R4-verified structure (split-K, 512 threads,
// K=32 PV via pre-permuted V image).  Only change vs R4: XCD-chunked work
// swizzle (T1).  Default dispatch round-robins consecutive block ids over
// the 8 XCDs, so the 32 blocks sharing one bh's KV (1 MB) spread across all
// 8 L2s -> ~8x KV over-fetch (FETCH_SIZE 70 MB vs ~24 ideal).  Chunked
// remap gives XCD k the works for bh {2k, 2k+1}: per-XCD set = 2 MB KV +
// 1 MB Q <= 4 MB L2.  Bijective: 512 blocks = 8 x 64 exactly.
// ---------------------------------------------------------------------------
__global__ __launch_bounds__(512, 4)
void flash_attn(const bh* __restrict__ Qb, const bh* __restrict__ KVf,
                bh* __restrict__ attb)
{
    __shared__ __align__(16) bh SF[2][2][KVBLK];   // [group][buf], 64 KB

    const int t = threadIdx.x;
    const int wave = t >> 6, lane = t & 63;
    const int group = wave >> 2, w4 = wave & 3;
    const int quad = lane >> 4, c16 = lane & 15;

    // XCD-chunked work swizzle: bid -> work, XCD(bid%8) gets works k*64..+63
    const int bid = blockIdx.x + blockIdx.y * 32;      // gridDim.x == 32
    const int work = (bid & 7) * 64 + (bid >> 3);      // bijective on [0,512)
    const int bh_idx = work >> 5;                      // work / 32
    const int q0 = (work & 31) * 128;

    const bh* Qp  = Qb + (size_t)bh_idx * NL * NDH;
    const bh* KVp = KVf + (size_t)bh_idx * 64 * KVBLK;

    bf16x8 qf[2][2];
    #pragma unroll
    for (int fq = 0; fq < 2; fq++)
        #pragma unroll
        for (int kc = 0; kc < 2; kc++)
            qf[fq][kc] = *(const bf16x8*)
                &Qp[(size_t)(q0 + w4 * 32 + fq * 16 + c16) * NDH + kc * 32 + quad * 8];

    f32x4 ot[4][2];
    float lsum[2] = {0.0f, 0.0f};
    for (int a = 0; a < 4; a++)
        for (int fq = 0; fq < 2; fq++)
            for (int u = 0; u < 4; u++) ot[a][fq][u] = 0.0f;
    const f32x4 z4 = {0.0f, 0.0f, 0.0f, 0.0f};

    auto stage = [&](int i, int buf) {
        int kt = 2 * i + group;
        #pragma unroll
        for (int r = 0; r < 4; r++) {
            int off = (w4 * 4 + r) * 512 + lane * 8;
            gload16(KVp + (size_t)kt * KVBLK + off, &SF[group][buf][off]);
        }
    };

    stage(0, 0);
    for (int i = 0; i < 32; i++) {
        const int buf = i & 1;
        __syncthreads();
        if (i < 31) stage(i + 1, buf ^ 1);
        const bh* sf = &SF[group][buf][0];

        // S^T = K Q^T; kc=0 consumes the zero-C operand directly
        f32x4 s[4][2];
        #pragma unroll
        for (int fk = 0; fk < 4; fk++) {
            bf16x8 kf0 = *(const bf16x8*)&sf[(fk * 2 + 0) * 512 + lane * 8];
            s[fk][0] = mfma_bf16(kf0, qf[0][0], z4);
            s[fk][1] = mfma_bf16(kf0, qf[1][0], z4);
        }
        #pragma unroll
        for (int fk = 0; fk < 4; fk++) {
            bf16x8 kf1 = *(const bf16x8*)&sf[(fk * 2 + 1) * 512 + lane * 8];
            s[fk][0] = mfma_bf16(kf1, qf[0][1], s[fk][0]);
            s[fk][1] = mfma_bf16(kf1, qf[1][1], s[fk][1]);
        }

        // V frags: 8x b128 (32-k interleaved image)
        bf16x8 vt[4][2];
        #pragma unroll
        for (int fn = 0; fn < 4; fn++)
            #pragma unroll
            for (int a = 0; a < 2; a++)
                vt[fn][a] = *(const bf16x8*)&sf[4096 + (fn * 2 + a) * 512 + lane * 8];

        float rs0 = 0.0f, rs1 = 0.0f;
        #pragma unroll
        for (int a = 0; a < 2; a++) {
            float a0 = __builtin_amdgcn_exp2f(s[2 * a][0][0]);
            float a1 = __builtin_amdgcn_exp2f(s[2 * a][0][1]);
            float a2 = __builtin_amdgcn_exp2f(s[2 * a][0][2]);
            float a3 = __builtin_amdgcn_exp2f(s[2 * a][0][3]);
            float a4 = __builtin_amdgcn_exp2f(s[2 * a + 1][0][0]);
            float a5 = __builtin_amdgcn_exp2f(s[2 * a + 1][0][1]);
            float a6 = __builtin_amdgcn_exp2f(s[2 * a + 1][0][2]);
            float a7 = __builtin_amdgcn_exp2f(s[2 * a + 1][0][3]);
            rs0 += ((a0 + a1) + (a2 + a3)) + ((a4 + a5) + (a6 + a7));
            bf16x8 p0 = pk_bf8(a0, a1, a2, a3, a4, a5, a6, a7);
            float b0 = __builtin_amdgcn_exp2f(s[2 * a][1][0]);
            float b1 = __builtin_amdgcn_exp2f(s[2 * a][1][1]);
            float b2 = __builtin_amdgcn_exp2f(s[2 * a][1][2]);
            float b3 = __builtin_amdgcn_exp2f(s[2 * a][1][3]);
            float b4 = __builtin_amdgcn_exp2f(s[2 * a + 1][1][0]);
            float b5 = __builtin_amdgcn_exp2f(s[2 * a + 1][1][1]);
            float b6 = __builtin_amdgcn_exp2f(s[2 * a + 1][1][2]);
            float b7 = __builtin_amdgcn_exp2f(s[2 * a + 1][1][3]);
            rs1 += ((b0 + b1) + (b2 + b3)) + ((b4 + b5) + (b6 + b7));
            bf16x8 p1 = pk_bf8(b0, b1, b2, b3, b4, b5, b6, b7);
            #pragma unroll
            for (int fn = 0; fn < 4; fn++) {
                ot[fn][0] = mfma_bf16(vt[fn][a], p0, ot[fn][0]);
                ot[fn][1] = mfma_bf16(vt[fn][a], p1, ot[fn][1]);
            }
        }
        lsum[0] += rs0;
        lsum[1] += rs1;
    }

    #pragma unroll
    for (int fq = 0; fq < 2; fq++) {
        lsum[fq] += __shfl_xor(lsum[fq], 16);
        lsum[fq] += __shfl_xor(lsum[fq], 32);
    }

    float* Ocmb = (float*)&SF[0][0][0];
    float* Lcmb = Ocmb + 128 * 64;
    __syncthreads();
    if (group == 1) {
        #pragma unroll
        for (int fq = 0; fq < 2; fq++) {
            int q = w4 * 32 + fq * 16 + c16;
            #pragma unroll
            for (int fn = 0; fn < 4; fn++)
                *(f32x4*)&Ocmb[q * 64 + fn * 16 + quad * 4] = ot[fn][fq];
            if (quad == 0) Lcmb[q] = lsum[fq];
        }
    }
    __syncthreads();
    if (group == 0) {
        const int b = bh_idx >> 3, h = bh_idx & 7;
        const int mbase16 = (b * NL + q0) >> 4;          // global row / 16 base
        #pragma unroll
        for (int fq = 0; fq < 2; fq++) {
            int q = w4 * 32 + fq * 16 + c16;
            float inv = 1.0f / (lsum[fq] + Lcmb[q]);
            int m16 = mbase16 + w4 * 2 + fq;
            #pragma unroll
            for (int fn = 0; fn < 4; fn++) {
                f32x4 o2 = *(const f32x4*)&Ocmb[q * 64 + fn * 16 + quad * 4];
                // A-frag scatter: block (m16, kcg = h*2 + (fn>>1)),
                // elem ((quad'*16 + c16)*8 + j0), quad' = (fn&1)*2 + (quad>>1)
                size_t addr = ((size_t)m16 * 16 + h * 2 + (fn >> 1)) * 512
                            + (size_t)(((fn & 1) * 2 + (quad >> 1)) * 16 + c16) * 8
                            + (quad & 1) * 4;
                st_bf4(&attb[addr],
                       (ot[fn][fq][0] + o2[0]) * inv, (ot[fn][fq][1] + o2[1]) * inv,
                       (ot[fn][fq][2] + o2[2]) * inv, (ot[fn][fq][3] + o2[3]) * inv);
            }
        }
    }
}

// ---------------------------------------------------------------------------
// Kernel 3: out = att(A-frag) @ Wo (pre-packed) + bo -> fp32 [B,L,C] (unchanged).
// ---------------------------------------------------------------------------
__global__ __launch_bounds__(256, 2)
void out_gemm(const bh* __restrict__ Af, const bh* __restrict__ Wf,
              const float* __restrict__ bo, float* __restrict__ out)
{
    __shared__ __align__(16) bh smem[2][12288];  // per buf: Xl 8192 + Wl 4096 (48 KB)

    const int t = threadIdx.x;
    const int wave = t >> 6, lane = t & 63;
    const int quad = lane >> 4, c16 = lane & 15;
    const int m0 = blockIdx.x * 128;
    const int nt = blockIdx.y;
    const int n0 = nt * 64;
    const int m16b = m0 >> 4;

    f32x4 acc[2][4];
    for (int a = 0; a < 2; a++)
        for (int b = 0; b < 4; b++)
            for (int u = 0; u < 4; u++) acc[a][b][u] = 0.0f;

    auto stage = [&](int k0i, int buf) {
        bh* Xl = &smem[buf][0];
        bh* Wl = &smem[buf][8192];
        #pragma unroll
        for (int r = 0; r < 4; r++) {
            int f = wave * 4 + r;
            const bh* src = Af + ((size_t)(m16b + (f >> 1)) * 16 + k0i * 2 + (f & 1)) * 512
                          + lane * 8;
            gload16(src, &Xl[f * 512 + lane * 8]);
        }
        const bh* wz = Wf + (((size_t)3 * 8 + nt) * 8 + k0i) * 4096;
        #pragma unroll
        for (int r = 0; r < 2; r++) {
            int off = (wave * 2 + r) * 512 + lane * 8;
            gload16(wz + off, &Wl[off]);
        }
    };

    stage(0, 0);
    for (int k0i = 0; k0i < 8; k0i++) {
        const int buf = k0i & 1;
        __syncthreads();
        if (k0i < 7) stage(k0i + 1, buf ^ 1);
        const bh* Xl = &smem[buf][0];
        const bh* Wl = &smem[buf][8192];
        #pragma unroll
        for (int kc = 0; kc < 2; kc++) {
            bf16x8 af0 = *(const bf16x8*)&Xl[((wave * 2 + 0) * 2 + kc) * 512 + lane * 8];
            bf16x8 af1 = *(const bf16x8*)&Xl[((wave * 2 + 1) * 2 + kc) * 512 + lane * 8];
            #pragma unroll
            for (int fn = 0; fn < 4; fn++) {
                bf16x8 bf = *(const bf16x8*)&Wl[(kc * 4 + fn) * 512 + lane * 8];
                acc[0][fn] = mfma_bf16(af0, bf, acc[0][fn]);
                acc[1][fn] = mfma_bf16(af1, bf, acc[1][fn]);
            }
        }
        __syncthreads();
    }

    #pragma unroll
    for (int fm = 0; fm < 2; fm++)
        #pragma unroll
        for (int i = 0; i < 4; i++) {
            int mr = m0 + wave * 32 + fm * 16 + quad * 4 + i;
            #pragma unroll
            for (int fn = 0; fn < 4; fn++) {
                int cn = n0 + fn * 16 + c16;
                out[(size_t)mr * 512 + cn] = acc[fm][fn][i] + bo[cn];
            }
        }
}

// ---------------------------------------------------------------------------
extern "C" void kernel_launch(void* const* d_in, const int* in_sizes, int n_in,
                              void* d_out, int out_size, void* d_ws, size_t ws_size,
                              hipStream_t stream)
{
    const float* x  = (const float*)d_in[0];
    const float* Wq = (const float*)d_in[1];
    const float* Wk = (const float*)d_in[2];
    const float* Wv = (const float*)d_in[3];
    const float* Wo = (const float*)d_in[4];
    const float* bo = (const float*)d_in[5];
    float* out = (float*)d_out;

    const size_t mat = (size_t)NM * NC;       // 4 Mi elems (8 MB bf16)
    bh* Qb   = (bh*)d_ws;                     //  8 MB
    bh* KVf  = Qb + mat;                      // 16 MB
    bh* attb = KVf + 2 * mat;                 //  8 MB (A-frag layout)
    bh* Wf   = attb + mat;                    //  2 MB
    bh* xf   = Wf + 4 * 8 * 8 * 4096;         //  8 MB

    prep      <<<dim3(128, 1, 9),         256, 0, stream>>>(x, Wq, Wk, Wv, Wo, xf, Wf);
    qkv_gemm  <<<dim3(NM / 128, NC / 64), 256, 0, stream>>>(xf, Wf, Qb, KVf);
    flash_attn<<<dim3(NL / 128, NB * NH), 512, 0, stream>>>(Qb, KVf, attb);
    out_gemm  <<<dim3(NM / 128, NC / 64), 256, 0, stream>>>(attb, Wf, bo, out);
}